// Round 1
// baseline (1270.540 us; speedup 1.0000x reference)
//
#include <hip/hip_runtime.h>
#include <hip/hip_bf16.h>

#define NN 50000
#define DM 256
#define NH 8
#define HD 32
#define DFF 512

__device__ __forceinline__ float leaky(float a) { return a > 0.f ? a : 0.2f * a; }

// ---------------------------------------------------------------------------
// Generic fp32 tiled GEMM: C = A[M,K] @ B[K,N] + bias (+residual) (+relu)
// BM=BN=128, BK=8, 256 threads, 8x8 microtile per thread.
// RES: 0=none, 1=plain residual, 2=residual with per-feature affine (r*ra+rb)
// AAFF: apply per-k affine to A on load (A' = A*ka[k] + kb[k])
// ---------------------------------------------------------------------------
template<int RELU, int RES, int AAFF>
__global__ __launch_bounds__(256) void gemm128(
    const float* __restrict__ A, const float* __restrict__ B,
    const float* __restrict__ bias, const float* __restrict__ res,
    const float* __restrict__ ka, const float* __restrict__ kb,
    const float* __restrict__ ra, const float* __restrict__ rb,
    float* __restrict__ Cout, int M, int K, int N)
{
    __shared__ float As[8][128];
    __shared__ float Bs[8][128];
    const int tid = threadIdx.x;
    const int tx = tid & 15, ty = tid >> 4;
    const int m0 = blockIdx.y * 128, n0 = blockIdx.x * 128;
    const int arow = tid >> 1, akc = (tid & 1) * 4;
    const int brow = tid >> 5, bcol = (tid & 31) * 4;

    float acc[8][8];
#pragma unroll
    for (int i = 0; i < 8; ++i)
#pragma unroll
        for (int j = 0; j < 8; ++j) acc[i][j] = 0.f;

    for (int k0 = 0; k0 < K; k0 += 8) {
        float4 av = make_float4(0.f, 0.f, 0.f, 0.f);
        const int gm = m0 + arow;
        if (gm < M) {
            av = *(const float4*)(A + (size_t)gm * K + k0 + akc);
            if (AAFF) {
                float4 sa = *(const float4*)(ka + k0 + akc);
                float4 sb = *(const float4*)(kb + k0 + akc);
                av.x = av.x * sa.x + sb.x;
                av.y = av.y * sa.y + sb.y;
                av.z = av.z * sa.z + sb.z;
                av.w = av.w * sa.w + sb.w;
            }
        }
        As[akc + 0][arow] = av.x;
        As[akc + 1][arow] = av.y;
        As[akc + 2][arow] = av.z;
        As[akc + 3][arow] = av.w;
        *(float4*)(&Bs[brow][bcol]) =
            *(const float4*)(B + (size_t)(k0 + brow) * N + n0 + bcol);
        __syncthreads();
#pragma unroll
        for (int k = 0; k < 8; ++k) {
            float a[8], b[8];
            *(float4*)(a)     = *(const float4*)&As[k][ty * 8];
            *(float4*)(a + 4) = *(const float4*)&As[k][ty * 8 + 4];
            *(float4*)(b)     = *(const float4*)&Bs[k][tx * 8];
            *(float4*)(b + 4) = *(const float4*)&Bs[k][tx * 8 + 4];
#pragma unroll
            for (int i = 0; i < 8; ++i)
#pragma unroll
                for (int j = 0; j < 8; ++j) acc[i][j] += a[i] * b[j];
        }
        __syncthreads();
    }

#pragma unroll
    for (int i = 0; i < 8; ++i) {
        const int gm = m0 + ty * 8 + i;
        if (gm >= M) continue;
#pragma unroll
        for (int j = 0; j < 8; j += 4) {
            const int gn = n0 + tx * 8 + j;
            float4 v = make_float4(acc[i][j], acc[i][j + 1], acc[i][j + 2], acc[i][j + 3]);
            float4 bb = *(const float4*)(bias + gn);
            v.x += bb.x; v.y += bb.y; v.z += bb.z; v.w += bb.w;
            if (RES == 1) {
                float4 r = *(const float4*)(res + (size_t)gm * N + gn);
                v.x += r.x; v.y += r.y; v.z += r.z; v.w += r.w;
            }
            if (RES == 2) {
                float4 r = *(const float4*)(res + (size_t)gm * N + gn);
                float4 sa = *(const float4*)(ra + gn);
                float4 sb = *(const float4*)(rb + gn);
                v.x += r.x * sa.x + sb.x;
                v.y += r.y * sa.y + sb.y;
                v.z += r.z * sa.z + sb.z;
                v.w += r.w * sa.w + sb.w;
            }
            if (RELU) {
                v.x = fmaxf(v.x, 0.f); v.y = fmaxf(v.y, 0.f);
                v.z = fmaxf(v.z, 0.f); v.w = fmaxf(v.w, 0.f);
            }
            *(float4*)(Cout + (size_t)gm * N + gn) = v;
        }
    }
}

// ---------------------------------------------------------------------------
// s[n,h] = dot(Q[n, h*32 : h*32+32], K[n, ...]) / sqrt(32)
// ---------------------------------------------------------------------------
__global__ __launch_bounds__(256) void score_kernel(
    const float* __restrict__ Q, const float* __restrict__ K,
    float* __restrict__ s)
{
    const int t = blockIdx.x * 256 + threadIdx.x;
    if (t >= NN * NH) return;
    const int n = t >> 3, h = t & 7;
    const float* q = Q + (size_t)n * DM + h * HD;
    const float* k = K + (size_t)n * DM + h * HD;
    float acc = 0.f;
#pragma unroll
    for (int c = 0; c < HD; c += 4) {
        float4 qa = *(const float4*)(q + c);
        float4 ka = *(const float4*)(k + c);
        acc += qa.x * ka.x + qa.y * ka.y + qa.z * ka.z + qa.w * ka.w;
    }
    s[t] = acc * 0.17677669529663687f;  // 1/sqrt(32)
}

// ---------------------------------------------------------------------------
// CSR build
// ---------------------------------------------------------------------------
__global__ __launch_bounds__(256) void hist_kernel(
    const int* __restrict__ dst, int* __restrict__ counts, int E)
{
    const int e = blockIdx.x * 256 + threadIdx.x;
    if (e < E) atomicAdd(&counts[dst[e]], 1);
}

__global__ __launch_bounds__(1024) void scan_kernel(
    const int* __restrict__ counts, int* __restrict__ offs,
    int* __restrict__ cursor, int n)
{
    __shared__ int lds[1024];
    __shared__ int srun;
    if (threadIdx.x == 0) srun = 0;
    __syncthreads();
    for (int base = 0; base < n; base += 1024) {
        const int i = base + threadIdx.x;
        const int v = (i < n) ? counts[i] : 0;
        lds[threadIdx.x] = v;
        __syncthreads();
#pragma unroll
        for (int off = 1; off < 1024; off <<= 1) {
            int t = (threadIdx.x >= off) ? lds[threadIdx.x - off] : 0;
            __syncthreads();
            lds[threadIdx.x] += t;
            __syncthreads();
        }
        const int run = srun;
        const int excl = run + lds[threadIdx.x] - v;
        if (i < n) { offs[i] = excl; cursor[i] = excl; }
        const int tot = lds[1023];
        __syncthreads();
        if (threadIdx.x == 0) srun = run + tot;
        __syncthreads();
    }
    if (threadIdx.x == 0) offs[n] = srun;
}

__global__ __launch_bounds__(256) void fill_kernel(
    const int* __restrict__ src, const int* __restrict__ dst,
    int* __restrict__ cursor, int* __restrict__ csr_src, int E)
{
    const int e = blockIdx.x * 256 + threadIdx.x;
    if (e >= E) return;
    const int p = atomicAdd(&cursor[dst[e]], 1);
    csr_src[p] = src[e];
}

// ---------------------------------------------------------------------------
// Per-node softmax-weighted aggregation. One 64-lane wave per node.
// attn[n,:] = sum_{e in in(n) ∪ self} softmax(leaky(s_src+s_dst))_e * V[src_e,:]
// ---------------------------------------------------------------------------
__global__ __launch_bounds__(256) void aggregate_kernel(
    const float* __restrict__ s, const float* __restrict__ V,
    const int* __restrict__ offs, const int* __restrict__ srcs,
    float* __restrict__ attn)
{
    const int n = (blockIdx.x * 256 + threadIdx.x) >> 6;
    const int lane = threadIdx.x & 63;
    if (n >= NN) return;
    const int base = offs[n];
    const int deg = offs[n + 1] - base;

    float sn[8];
    *(float4*)(sn)     = *(const float4*)(s + (size_t)n * 8);
    *(float4*)(sn + 4) = *(const float4*)(s + (size_t)n * 8 + 4);

    // pass 1: max (init with self-loop alpha = leaky(2*s_n))
    float mx[8];
#pragma unroll
    for (int h = 0; h < 8; ++h) mx[h] = leaky(2.f * sn[h]);
    for (int i = lane; i < deg; i += 64) {
        const int sr = srcs[base + i];
        float ss[8];
        *(float4*)(ss)     = *(const float4*)(s + (size_t)sr * 8);
        *(float4*)(ss + 4) = *(const float4*)(s + (size_t)sr * 8 + 4);
#pragma unroll
        for (int h = 0; h < 8; ++h) mx[h] = fmaxf(mx[h], leaky(sn[h] + ss[h]));
    }
#pragma unroll
    for (int off = 32; off > 0; off >>= 1)
#pragma unroll
        for (int h = 0; h < 8; ++h) mx[h] = fmaxf(mx[h], __shfl_xor(mx[h], off));

    // pass 2: denom
    float sm[8] = {0.f, 0.f, 0.f, 0.f, 0.f, 0.f, 0.f, 0.f};
    for (int i = lane; i < deg; i += 64) {
        const int sr = srcs[base + i];
        float ss[8];
        *(float4*)(ss)     = *(const float4*)(s + (size_t)sr * 8);
        *(float4*)(ss + 4) = *(const float4*)(s + (size_t)sr * 8 + 4);
#pragma unroll
        for (int h = 0; h < 8; ++h) sm[h] += __expf(leaky(sn[h] + ss[h]) - mx[h]);
    }
#pragma unroll
    for (int off = 32; off > 0; off >>= 1)
#pragma unroll
        for (int h = 0; h < 8; ++h) sm[h] += __shfl_xor(sm[h], off);
#pragma unroll
    for (int h = 0; h < 8; ++h) sm[h] += __expf(leaky(2.f * sn[h]) - mx[h]);  // self

    // pass 3: weighted V accumulation; lane owns 4 features (head h0)
    const int h0 = lane >> 3;
    const int f0 = lane * 4;
    const float snh = sn[h0], mxh = mx[h0];
    const float rdh = 1.f / sm[h0];

    float4 acc;
    {
        const float w = __expf(leaky(2.f * snh) - mxh) * rdh;  // self
        float4 vv = *(const float4*)(V + (size_t)n * DM + f0);
        acc.x = w * vv.x; acc.y = w * vv.y; acc.z = w * vv.z; acc.w = w * vv.w;
    }
    for (int i = 0; i < deg; ++i) {
        const int sr = srcs[base + i];
        const float sv = s[(size_t)sr * 8 + h0];
        const float w = __expf(leaky(snh + sv) - mxh) * rdh;
        float4 vv = *(const float4*)(V + (size_t)sr * DM + f0);
        acc.x += w * vv.x; acc.y += w * vv.y; acc.z += w * vv.z; acc.w += w * vv.w;
    }
    *(float4*)(attn + (size_t)n * DM + f0) = acc;
}

// ---------------------------------------------------------------------------
// BatchNorm: per-feature sum & sumsq reduction, then affine fold
// ---------------------------------------------------------------------------
__global__ __launch_bounds__(256) void bn_stats_kernel(
    const float* __restrict__ y, float* __restrict__ sums)
{
    const int f = threadIdx.x;
    float s = 0.f, q = 0.f;
    for (int r = blockIdx.x; r < NN; r += gridDim.x) {
        const float v = y[(size_t)r * DM + f];
        s += v; q += v * v;
    }
    atomicAdd(&sums[f], s);
    atomicAdd(&sums[DM + f], q);
}

__global__ __launch_bounds__(256) void bn_final_kernel(
    const float* __restrict__ sums, const float* __restrict__ g,
    const float* __restrict__ b, float* __restrict__ sc, float* __restrict__ sh)
{
    const int f = threadIdx.x;
    const float invM = 1.f / (float)NN;
    const float mean = sums[f] * invM;
    const float var = sums[DM + f] * invM - mean * mean;
    const float a = g[f] * rsqrtf(var + 1e-5f);
    sc[f] = a;
    sh[f] = b[f] - mean * a;
}

__global__ __launch_bounds__(256) void apply_kernel(
    const float* __restrict__ z, const float* __restrict__ sc,
    const float* __restrict__ sh, float* __restrict__ out)
{
    const size_t total4 = (size_t)NN * DM / 4;
    for (size_t i = blockIdx.x * 256 + threadIdx.x; i < total4; i += (size_t)gridDim.x * 256) {
        const int f0 = (int)((i * 4) & (DM - 1));
        float4 v = *(const float4*)(z + i * 4);
        float4 a = *(const float4*)(sc + f0);
        float4 b = *(const float4*)(sh + f0);
        v.x = v.x * a.x + b.x;
        v.y = v.y * a.y + b.y;
        v.z = v.z * a.z + b.z;
        v.w = v.w * a.w + b.w;
        *(float4*)(out + i * 4) = v;
    }
}

// ---------------------------------------------------------------------------
extern "C" void kernel_launch(void* const* d_in, const int* in_sizes, int n_in,
                              void* d_out, int out_size, void* d_ws, size_t ws_size,
                              hipStream_t stream)
{
    const float* x   = (const float*)d_in[0];
    const int* eidx  = (const int*)d_in[1];
    const int E      = in_sizes[1] / 2;
    const int* esrc  = eidx;
    const int* edst  = eidx + E;
    const float* Wq = (const float*)d_in[2];  const float* bq = (const float*)d_in[3];
    const float* Wk = (const float*)d_in[4];  const float* bk = (const float*)d_in[5];
    const float* Wv = (const float*)d_in[6];  const float* bv = (const float*)d_in[7];
    const float* Wo = (const float*)d_in[8];  const float* bo = (const float*)d_in[9];
    const float* W1 = (const float*)d_in[10]; const float* b1 = (const float*)d_in[11];
    const float* W2 = (const float*)d_in[12]; const float* b2 = (const float*)d_in[13];
    const float* g1 = (const float*)d_in[14]; const float* be1 = (const float*)d_in[15];
    const float* g2 = (const float*)d_in[16]; const float* be2 = (const float*)d_in[17];
    float* out = (float*)d_out;

    // workspace layout
    const size_t NDM = (size_t)NN * DM;  // 12.8M floats
    float* buf0 = (float*)d_ws;          // Q -> attn ; also first half of ff1
    float* buf2 = buf0 + NDM;            // V        ; second half of ff1
    float* buf1 = buf2 + NDM;            // K -> h (y, then z)
    float* ff1  = buf0;                  // [NN, 512] spans buf0+buf2
    float* sS   = buf1 + NDM;            // [NN, 8]
    int* counts = (int*)(sS + (size_t)NN * NH);
    int* offs   = counts + NN;           // NN+1
    int* cursor = offs + NN + 1;
    int* csr    = cursor + NN;           // E
    float* bnsum = (float*)(csr + E);    // 512
    float* sc1 = bnsum + 2 * DM;
    float* sh1 = sc1 + DM;
    float* sc2 = sh1 + DM;
    float* sh2 = sc2 + DM;

    const dim3 blk(256);
    const dim3 gemm_grid(DM / 128, (NN + 127) / 128);      // 2 x 391
    const dim3 gemm_grid_ff(DFF / 128, (NN + 127) / 128);  // 4 x 391

    // --- Q, K, V projections ---
    gemm128<0, 0, 0><<<gemm_grid, blk, 0, stream>>>(x, Wq, bq, nullptr, nullptr, nullptr,
                                                    nullptr, nullptr, buf0, NN, DM, DM);
    gemm128<0, 0, 0><<<gemm_grid, blk, 0, stream>>>(x, Wk, bk, nullptr, nullptr, nullptr,
                                                    nullptr, nullptr, buf1, NN, DM, DM);
    gemm128<0, 0, 0><<<gemm_grid, blk, 0, stream>>>(x, Wv, bv, nullptr, nullptr, nullptr,
                                                    nullptr, nullptr, buf2, NN, DM, DM);

    // --- per-node scores ---
    score_kernel<<<(NN * NH + 255) / 256, blk, 0, stream>>>(buf0, buf1, sS);

    // --- CSR over destination ---
    hipMemsetAsync(counts, 0, sizeof(int) * NN, stream);
    hist_kernel<<<(E + 255) / 256, blk, 0, stream>>>(edst, counts, E);
    scan_kernel<<<1, 1024, 0, stream>>>(counts, offs, cursor, NN);
    fill_kernel<<<(E + 255) / 256, blk, 0, stream>>>(esrc, edst, cursor, csr, E);

    // --- softmax + V aggregation (overwrites Q buffer) ---
    aggregate_kernel<<<(NN + 3) / 4, blk, 0, stream>>>(sS, buf2, offs, csr, buf0);

    // --- output projection + residual: y = x + attn @ Wo + bo  (overwrites K buf) ---
    gemm128<0, 1, 0><<<gemm_grid, blk, 0, stream>>>(buf0, Wo, bo, x, nullptr, nullptr,
                                                    nullptr, nullptr, buf1, NN, DM, DM);

    // --- BN1 stats -> (sc1, sh1) ---
    hipMemsetAsync(bnsum, 0, sizeof(float) * 2 * DM, stream);
    bn_stats_kernel<<<256, blk, 0, stream>>>(buf1, bnsum);
    bn_final_kernel<<<1, blk, 0, stream>>>(bnsum, g1, be1, sc1, sh1);

    // --- FF1: ff1 = relu(norm(y) @ W1 + b1), norm applied on A-load ---
    gemm128<1, 0, 1><<<gemm_grid_ff, blk, 0, stream>>>(buf1, W1, b1, nullptr, sc1, sh1,
                                                       nullptr, nullptr, ff1, NN, DM, DFF);

    // --- FF2 + residual: z = norm(y) + ff1 @ W2 + b2  (in-place on buf1) ---
    gemm128<0, 2, 0><<<gemm_grid, blk, 0, stream>>>(ff1, W2, b2, buf1, nullptr, nullptr,
                                                    sc1, sh1, buf1, NN, DFF, DM);

    // --- BN2 stats -> (sc2, sh2), final apply -> out ---
    hipMemsetAsync(bnsum, 0, sizeof(float) * 2 * DM, stream);
    bn_stats_kernel<<<256, blk, 0, stream>>>(buf1, bnsum);
    bn_final_kernel<<<1, blk, 0, stream>>>(bnsum, g2, be2, sc2, sh2);
    apply_kernel<<<2048, blk, 0, stream>>>(buf1, sc2, sh2, out);
}

// Round 2
// 674.472 us; speedup vs baseline: 1.8838x; 1.8838x over previous
//
#include <hip/hip_runtime.h>
#include <hip/hip_bf16.h>

#define NN 50000
#define MP 50048      // 391 * 128 (padded rows for tile staging)
#define DM 256
#define NH 8
#define HD 32
#define DFF 512
#define DQKV 768

typedef unsigned short u16;
typedef __attribute__((ext_vector_type(8))) short bf16x8;
typedef __attribute__((ext_vector_type(4))) short bf16x4;
typedef __attribute__((ext_vector_type(4))) float f32x4;

__device__ __forceinline__ float leaky(float a) { return a > 0.f ? a : 0.2f * a; }

__device__ __forceinline__ float b2f(u16 s) {
    union { float f; unsigned u; } v; v.u = ((unsigned)s) << 16; return v.f;
}
__device__ __forceinline__ u16 f2b(float f) {
    union { float f; unsigned u; } v; v.f = f;
    unsigned r = v.u + 0x7FFFu + ((v.u >> 16) & 1u);
    return (u16)(r >> 16);
}

#define ASYNC16(gp, lp) __builtin_amdgcn_global_load_lds( \
    (const __attribute__((address_space(1))) void*)(gp),  \
    (__attribute__((address_space(3))) void*)(lp), 16, 0, 0)

// ---------------------------------------------------------------------------
// bf16 MFMA GEMM: C[M,N](bf16) = A[Mpad,K](bf16) @ Bt[N,K]^T + bias (+res)(+relu)
// 128x128 tile, BK=64, 256 threads = 4 waves (2x2), 4x4 16x16x32 frags/wave.
// RES: 0 none, 1 fp32 residual, 2 bf16 residual.
// ---------------------------------------------------------------------------
template<int RELU, int RES>
__global__ __launch_bounds__(256) void gemm_bf16(
    const u16* __restrict__ A, const u16* __restrict__ Bt,
    const float* __restrict__ bias, const void* __restrict__ res,
    u16* __restrict__ C, int M, int K, int N)
{
    __shared__ u16 As[128][64];
    __shared__ u16 Bs[128][64];
    const int tid = threadIdx.x;
    const int wave = tid >> 6, lane = tid & 63;
    const int m0 = blockIdx.y * 128, n0 = blockIdx.x * 128;
    const int wr = (wave >> 1) * 64, wc = (wave & 1) * 64;

    f32x4 acc[4][4] = {};

    // staging: each wave stages 32 rows of A and 32 rows of Bt per K-step.
    // one global_load_lds(16B): 64 lanes -> 1KB = 8 rows of 128B.
    const int srow = wave * 32 + (lane >> 3);
    const int scol = (lane & 7) * 8;

    for (int k0 = 0; k0 < K; k0 += 64) {
#pragma unroll
        for (int i = 0; i < 4; ++i)
            ASYNC16(A + (size_t)(m0 + srow + i * 8) * K + k0 + scol,
                    &As[wave * 32 + i * 8][0]);
#pragma unroll
        for (int i = 0; i < 4; ++i)
            ASYNC16(Bt + (size_t)(n0 + srow + i * 8) * K + k0 + scol,
                    &Bs[wave * 32 + i * 8][0]);
        __syncthreads();
#pragma unroll
        for (int kk = 0; kk < 64; kk += 32) {
            bf16x8 av[4], bv[4];
#pragma unroll
            for (int m = 0; m < 4; ++m)
                av[m] = *(const bf16x8*)&As[wr + m * 16 + (lane & 15)][kk + (lane >> 4) * 8];
#pragma unroll
            for (int n = 0; n < 4; ++n)
                bv[n] = *(const bf16x8*)&Bs[wc + n * 16 + (lane & 15)][kk + (lane >> 4) * 8];
#pragma unroll
            for (int m = 0; m < 4; ++m)
#pragma unroll
                for (int n = 0; n < 4; ++n)
                    acc[m][n] = __builtin_amdgcn_mfma_f32_16x16x32_bf16(
                        av[m], bv[n], acc[m][n], 0, 0, 0);
        }
        __syncthreads();
    }

    // epilogue: C/D layout col = lane&15, row = (lane>>4)*4 + reg  [m89-verified]
    const int col_l = lane & 15, rgrp = (lane >> 4) * 4;
#pragma unroll
    for (int m = 0; m < 4; ++m) {
#pragma unroll
        for (int r = 0; r < 4; ++r) {
            const int row = m0 + wr + m * 16 + rgrp + r;
            if (row >= M) continue;
#pragma unroll
            for (int n = 0; n < 4; ++n) {
                const int col = n0 + wc + n * 16 + col_l;
                float v = acc[m][n][r] + bias[col];
                if (RES == 1) v += ((const float*)res)[(size_t)row * N + col];
                if (RES == 2) v += b2f(((const u16*)res)[(size_t)row * N + col]);
                if (RELU) v = fmaxf(v, 0.f);
                C[(size_t)row * N + col] = f2b(v);
            }
        }
    }
}

// ---------------------------------------------------------------------------
// fp32 -> bf16 cast (x -> xb)
// ---------------------------------------------------------------------------
__global__ __launch_bounds__(256) void cast_kernel(
    const float* __restrict__ x, u16* __restrict__ xb)
{
    const size_t i = ((size_t)blockIdx.x * 256 + threadIdx.x) * 8;
    if (i >= (size_t)NN * DM) return;
    float4 a = *(const float4*)(x + i);
    float4 b = *(const float4*)(x + i + 4);
    u16 o[8] = {f2b(a.x), f2b(a.y), f2b(a.z), f2b(a.w),
                f2b(b.x), f2b(b.y), f2b(b.z), f2b(b.w)};
    *(bf16x8*)(xb + i) = *(bf16x8*)o;
}

// ---------------------------------------------------------------------------
// weight transpose+cast: out[n][k] = (bf16) W[k][n]   (W is [K,N] fp32)
// ---------------------------------------------------------------------------
__global__ __launch_bounds__(256) void wtrans_kernel(
    const float* __restrict__ W, u16* __restrict__ out, int K, int N)
{
    const int n = blockIdx.x;
    for (int k = threadIdx.x; k < K; k += 256)
        out[(size_t)n * K + k] = f2b(W[(size_t)k * N + n]);
}

__global__ __launch_bounds__(256) void bias3_kernel(
    const float* __restrict__ a, const float* __restrict__ b,
    const float* __restrict__ c, float* __restrict__ o)
{
    const int t = threadIdx.x;
    o[t] = a[t]; o[t + 256] = b[t]; o[t + 512] = c[t];
}

// ---------------------------------------------------------------------------
// s[n,h] = dot(Q[n,h], K[n,h]) / sqrt(32)   (Q,K inside packed QKV bf16)
// ---------------------------------------------------------------------------
__global__ __launch_bounds__(256) void score_kernel(
    const u16* __restrict__ QKV, float* __restrict__ s)
{
    const int t = blockIdx.x * 256 + threadIdx.x;
    if (t >= NN * NH) return;
    const int n = t >> 3, h = t & 7;
    const u16* q = QKV + (size_t)n * DQKV + h * HD;
    const u16* k = q + DM;
    float acc = 0.f;
#pragma unroll
    for (int c = 0; c < HD; c += 8) {
        bf16x8 qa = *(const bf16x8*)(q + c);
        bf16x8 ka = *(const bf16x8*)(k + c);
#pragma unroll
        for (int j = 0; j < 8; ++j)
            acc += b2f((u16)qa[j]) * b2f((u16)ka[j]);
    }
    s[t] = acc * 0.17677669529663687f;
}

// ---------------------------------------------------------------------------
// CSR build
// ---------------------------------------------------------------------------
__global__ __launch_bounds__(256) void hist_kernel(
    const int* __restrict__ dst, int* __restrict__ counts, int E)
{
    const int e = blockIdx.x * 256 + threadIdx.x;
    if (e < E) atomicAdd(&counts[dst[e]], 1);
}

__global__ __launch_bounds__(1024) void scan_kernel(
    const int* __restrict__ counts, int* __restrict__ offs,
    int* __restrict__ cursor, int n)
{
    __shared__ int lds[1024];
    __shared__ int srun;
    if (threadIdx.x == 0) srun = 0;
    __syncthreads();
    for (int base = 0; base < n; base += 1024) {
        const int i = base + threadIdx.x;
        const int v = (i < n) ? counts[i] : 0;
        lds[threadIdx.x] = v;
        __syncthreads();
#pragma unroll
        for (int off = 1; off < 1024; off <<= 1) {
            int t = (threadIdx.x >= off) ? lds[threadIdx.x - off] : 0;
            __syncthreads();
            lds[threadIdx.x] += t;
            __syncthreads();
        }
        const int run = srun;
        const int excl = run + lds[threadIdx.x] - v;
        if (i < n) { offs[i] = excl; cursor[i] = excl; }
        const int tot = lds[1023];
        __syncthreads();
        if (threadIdx.x == 0) srun = run + tot;
        __syncthreads();
    }
    if (threadIdx.x == 0) offs[n] = srun;
}

__global__ __launch_bounds__(256) void fill_kernel(
    const int* __restrict__ src, const int* __restrict__ dst,
    int* __restrict__ cursor, int* __restrict__ csr_src, int E)
{
    const int e = blockIdx.x * 256 + threadIdx.x;
    if (e >= E) return;
    const int p = atomicAdd(&cursor[dst[e]], 1);
    csr_src[p] = src[e];
}

// ---------------------------------------------------------------------------
// softmax-weighted V aggregation, one wave per node. V lives inside QKV (+512).
// ---------------------------------------------------------------------------
__global__ __launch_bounds__(256) void aggregate_kernel(
    const float* __restrict__ s, const u16* __restrict__ QKV,
    const int* __restrict__ offs, const int* __restrict__ srcs,
    u16* __restrict__ attn)
{
    const int n = (blockIdx.x * 256 + threadIdx.x) >> 6;
    const int lane = threadIdx.x & 63;
    if (n >= NN) return;
    const int base = offs[n];
    const int deg = offs[n + 1] - base;

    float sn[8];
    *(float4*)(sn)     = *(const float4*)(s + (size_t)n * 8);
    *(float4*)(sn + 4) = *(const float4*)(s + (size_t)n * 8 + 4);

    float mx[8];
#pragma unroll
    for (int h = 0; h < 8; ++h) mx[h] = leaky(2.f * sn[h]);
    for (int i = lane; i < deg; i += 64) {
        const int sr = srcs[base + i];
        float ss[8];
        *(float4*)(ss)     = *(const float4*)(s + (size_t)sr * 8);
        *(float4*)(ss + 4) = *(const float4*)(s + (size_t)sr * 8 + 4);
#pragma unroll
        for (int h = 0; h < 8; ++h) mx[h] = fmaxf(mx[h], leaky(sn[h] + ss[h]));
    }
#pragma unroll
    for (int off = 32; off > 0; off >>= 1)
#pragma unroll
        for (int h = 0; h < 8; ++h) mx[h] = fmaxf(mx[h], __shfl_xor(mx[h], off));

    float sm[8] = {0.f, 0.f, 0.f, 0.f, 0.f, 0.f, 0.f, 0.f};
    for (int i = lane; i < deg; i += 64) {
        const int sr = srcs[base + i];
        float ss[8];
        *(float4*)(ss)     = *(const float4*)(s + (size_t)sr * 8);
        *(float4*)(ss + 4) = *(const float4*)(s + (size_t)sr * 8 + 4);
#pragma unroll
        for (int h = 0; h < 8; ++h) sm[h] += __expf(leaky(sn[h] + ss[h]) - mx[h]);
    }
#pragma unroll
    for (int off = 32; off > 0; off >>= 1)
#pragma unroll
        for (int h = 0; h < 8; ++h) sm[h] += __shfl_xor(sm[h], off);
#pragma unroll
    for (int h = 0; h < 8; ++h) sm[h] += __expf(leaky(2.f * sn[h]) - mx[h]);

    const int h0 = lane >> 3;
    const int f0 = lane * 4;
    const float snh = sn[h0], mxh = mx[h0];
    const float rdh = 1.f / sm[h0];

    float a0, a1, a2, a3;
    {
        const float w = __expf(leaky(2.f * snh) - mxh) * rdh;
        bf16x4 vv = *(const bf16x4*)(QKV + (size_t)n * DQKV + 2 * DM + f0);
        a0 = w * b2f((u16)vv[0]); a1 = w * b2f((u16)vv[1]);
        a2 = w * b2f((u16)vv[2]); a3 = w * b2f((u16)vv[3]);
    }
    for (int i = 0; i < deg; ++i) {
        const int sr = srcs[base + i];
        const float sv = s[(size_t)sr * 8 + h0];
        const float w = __expf(leaky(snh + sv) - mxh) * rdh;
        bf16x4 vv = *(const bf16x4*)(QKV + (size_t)sr * DQKV + 2 * DM + f0);
        a0 += w * b2f((u16)vv[0]); a1 += w * b2f((u16)vv[1]);
        a2 += w * b2f((u16)vv[2]); a3 += w * b2f((u16)vv[3]);
    }
    u16 o[4] = {f2b(a0), f2b(a1), f2b(a2), f2b(a3)};
    *(bf16x4*)(attn + (size_t)n * DM + f0) = *(bf16x4*)o;
}

// ---------------------------------------------------------------------------
// BatchNorm pieces (stats on bf16 tensor)
// ---------------------------------------------------------------------------
__global__ __launch_bounds__(256) void bn_stats_kernel(
    const u16* __restrict__ y, float* __restrict__ sums)
{
    const int f = threadIdx.x;
    float s = 0.f, q = 0.f;
    for (int r = blockIdx.x; r < NN; r += gridDim.x) {
        const float v = b2f(y[(size_t)r * DM + f]);
        s += v; q += v * v;
    }
    atomicAdd(&sums[f], s);
    atomicAdd(&sums[DM + f], q);
}

__global__ __launch_bounds__(256) void bn_final_kernel(
    const float* __restrict__ sums, const float* __restrict__ g,
    const float* __restrict__ b, float* __restrict__ sc, float* __restrict__ sh)
{
    const int f = threadIdx.x;
    const float invM = 1.f / (float)NN;
    const float mean = sums[f] * invM;
    const float var = sums[DM + f] * invM - mean * mean;
    const float a = g[f] * rsqrtf(var + 1e-5f);
    sc[f] = a;
    sh[f] = b[f] - mean * a;
}

// y (bf16) = y*sc + sh, in place
__global__ __launch_bounds__(256) void apply_bf_kernel(
    u16* __restrict__ y, const float* __restrict__ sc, const float* __restrict__ sh)
{
    const size_t i = ((size_t)blockIdx.x * 256 + threadIdx.x) * 8;
    if (i >= (size_t)NN * DM) return;
    const int f0 = (int)(i & (DM - 1));
    bf16x8 v = *(bf16x8*)(y + i);
    u16 o[8];
#pragma unroll
    for (int j = 0; j < 8; ++j)
        o[j] = f2b(b2f((u16)v[j]) * sc[f0 + j] + sh[f0 + j]);
    *(bf16x8*)(y + i) = *(bf16x8*)o;
}

// out (fp32) = z(bf16)*sc + sh
__global__ __launch_bounds__(256) void apply_out_kernel(
    const u16* __restrict__ z, const float* __restrict__ sc,
    const float* __restrict__ sh, float* __restrict__ out)
{
    const size_t i = ((size_t)blockIdx.x * 256 + threadIdx.x) * 8;
    if (i >= (size_t)NN * DM) return;
    const int f0 = (int)(i & (DM - 1));
    bf16x8 v = *(const bf16x8*)(z + i);
    float4 o0, o1;
    o0.x = b2f((u16)v[0]) * sc[f0 + 0] + sh[f0 + 0];
    o0.y = b2f((u16)v[1]) * sc[f0 + 1] + sh[f0 + 1];
    o0.z = b2f((u16)v[2]) * sc[f0 + 2] + sh[f0 + 2];
    o0.w = b2f((u16)v[3]) * sc[f0 + 3] + sh[f0 + 3];
    o1.x = b2f((u16)v[4]) * sc[f0 + 4] + sh[f0 + 4];
    o1.y = b2f((u16)v[5]) * sc[f0 + 5] + sh[f0 + 5];
    o1.z = b2f((u16)v[6]) * sc[f0 + 6] + sh[f0 + 6];
    o1.w = b2f((u16)v[7]) * sc[f0 + 7] + sh[f0 + 7];
    *(float4*)(out + i)     = o0;
    *(float4*)(out + i + 4) = o1;
}

// ---------------------------------------------------------------------------
extern "C" void kernel_launch(void* const* d_in, const int* in_sizes, int n_in,
                              void* d_out, int out_size, void* d_ws, size_t ws_size,
                              hipStream_t stream)
{
    const float* x   = (const float*)d_in[0];
    const int* eidx  = (const int*)d_in[1];
    const int E      = in_sizes[1] / 2;
    const int* esrc  = eidx;
    const int* edst  = eidx + E;
    const float* Wq = (const float*)d_in[2];  const float* bq = (const float*)d_in[3];
    const float* Wk = (const float*)d_in[4];  const float* bk = (const float*)d_in[5];
    const float* Wv = (const float*)d_in[6];  const float* bv = (const float*)d_in[7];
    const float* Wo = (const float*)d_in[8];  const float* bo = (const float*)d_in[9];
    const float* W1 = (const float*)d_in[10]; const float* b1 = (const float*)d_in[11];
    const float* W2 = (const float*)d_in[12]; const float* b2 = (const float*)d_in[13];
    const float* g1 = (const float*)d_in[14]; const float* be1 = (const float*)d_in[15];
    const float* g2 = (const float*)d_in[16]; const float* be2 = (const float*)d_in[17];
    float* out = (float*)d_out;

    // ---- workspace layout (bf16 = u16), ~130 MB total ----
    u16* xb   = (u16*)d_ws;                       // [MP*DM]   xb -> y -> yn
    u16* qkv  = xb + (size_t)MP * DM;             // [MP*DQKV] QKV -> ff1
    u16* attn = qkv + (size_t)MP * DQKV;          // [MP*DM]   attn -> z
    float* sS = (float*)(attn + (size_t)MP * DM); // [NN*8]
    int* counts = (int*)(sS + (size_t)NN * NH);
    int* offs   = counts + NN;                    // NN+1
    int* cursor = offs + NN + 1;
    int* csr    = cursor + NN;                    // E
    uintptr_t p = (uintptr_t)(csr + E);
    p = (p + 15) & ~(uintptr_t)15;
    u16* wqkvt = (u16*)p;                         // [768*256]
    u16* wot   = wqkvt + 768 * 256;               // [256*256]
    u16* w1t   = wot + 256 * 256;                 // [512*256]
    u16* w2t   = w1t + 512 * 256;                 // [256*512]
    float* bqkv = (float*)(w2t + 256 * 512);      // [768]
    float* bnsum = bqkv + 768;                    // [512]
    float* sc1 = bnsum + 512;
    float* sh1 = sc1 + DM;
    float* sc2 = sh1 + DM;
    float* sh2 = sc2 + DM;

    const dim3 blk(256);
    const int elem_grid = (NN * DM / 8 + 255) / 256;

    // ---- prep: casts & weight packing ----
    cast_kernel<<<elem_grid, blk, 0, stream>>>(x, xb);
    wtrans_kernel<<<256, blk, 0, stream>>>(Wq, wqkvt,             DM, DM);
    wtrans_kernel<<<256, blk, 0, stream>>>(Wk, wqkvt + 256 * 256, DM, DM);
    wtrans_kernel<<<256, blk, 0, stream>>>(Wv, wqkvt + 512 * 256, DM, DM);
    wtrans_kernel<<<256, blk, 0, stream>>>(Wo, wot, DM, DM);
    wtrans_kernel<<<512, blk, 0, stream>>>(W1, w1t, DM, DFF);
    wtrans_kernel<<<256, blk, 0, stream>>>(W2, w2t, DFF, DM);
    bias3_kernel<<<1, blk, 0, stream>>>(bq, bk, bv, bqkv);

    // ---- CSR over destinations (independent of GEMMs) ----
    hipMemsetAsync(counts, 0, sizeof(int) * NN, stream);
    hist_kernel<<<(E + 255) / 256, blk, 0, stream>>>(edst, counts, E);
    scan_kernel<<<1, 1024, 0, stream>>>(counts, offs, cursor, NN);
    fill_kernel<<<(E + 255) / 256, blk, 0, stream>>>(esrc, edst, cursor, csr, E);

    // ---- fused QKV projection ----
    gemm_bf16<0, 0><<<dim3(DQKV / 128, MP / 128), blk, 0, stream>>>(
        xb, wqkvt, bqkv, nullptr, qkv, NN, DM, DQKV);

    // ---- per-node scores ----
    score_kernel<<<(NN * NH + 255) / 256, blk, 0, stream>>>(qkv, sS);

    // ---- softmax + V aggregation ----
    aggregate_kernel<<<(NN + 3) / 4, blk, 0, stream>>>(sS, qkv, offs, csr, attn);

    // ---- O-projection + residual: y = x + attn @ Wo + bo (into xb region) ----
    gemm_bf16<0, 1><<<dim3(DM / 128, MP / 128), blk, 0, stream>>>(
        attn, wot, bo, x, xb, NN, DM, DM);

    // ---- BN1 -> apply in place (y -> yn) ----
    hipMemsetAsync(bnsum, 0, sizeof(float) * 2 * DM, stream);
    bn_stats_kernel<<<256, blk, 0, stream>>>(xb, bnsum);
    bn_final_kernel<<<1, blk, 0, stream>>>(bnsum, g1, be1, sc1, sh1);
    apply_bf_kernel<<<elem_grid, blk, 0, stream>>>(xb, sc1, sh1);

    // ---- FF1: ff1 = relu(yn @ W1 + b1)  (into qkv region) ----
    gemm_bf16<1, 0><<<dim3(DFF / 128, MP / 128), blk, 0, stream>>>(
        xb, w1t, b1, nullptr, qkv, NN, DM, DFF);

    // ---- FF2 + residual: z = yn + ff1 @ W2 + b2  (into attn region) ----
    gemm_bf16<0, 2><<<dim3(DM / 128, MP / 128), blk, 0, stream>>>(
        qkv, w2t, b2, xb, attn, NN, DFF, DM);

    // ---- BN2 -> out (fp32) ----
    hipMemsetAsync(bnsum, 0, sizeof(float) * 2 * DM, stream);
    bn_stats_kernel<<<256, blk, 0, stream>>>(attn, bnsum);
    bn_final_kernel<<<1, blk, 0, stream>>>(bnsum, g2, be2, sc2, sh2);
    apply_out_kernel<<<elem_grid, blk, 0, stream>>>(attn, sc2, sh2, out);
}

// Round 3
// 545.932 us; speedup vs baseline: 2.3273x; 1.2355x over previous
//
#include <hip/hip_runtime.h>
#include <hip/hip_bf16.h>

#define NN 50000
#define MP 50048      // 391 * 128 (padded rows for tile staging)
#define DM 256
#define NH 8
#define HD 32
#define DFF 512
#define DQKV 768

typedef unsigned short u16;
typedef __attribute__((ext_vector_type(8))) short bf16x8;
typedef __attribute__((ext_vector_type(4))) short bf16x4;
typedef __attribute__((ext_vector_type(4))) float f32x4;

__device__ __forceinline__ float leaky(float a) { return a > 0.f ? a : 0.2f * a; }

__device__ __forceinline__ float b2f(u16 s) {
    union { float f; unsigned u; } v; v.u = ((unsigned)s) << 16; return v.f;
}
__device__ __forceinline__ u16 f2b(float f) {
    union { float f; unsigned u; } v; v.f = f;
    unsigned r = v.u + 0x7FFFu + ((v.u >> 16) & 1u);
    return (u16)(r >> 16);
}

#define ASYNC16(gp, lp) __builtin_amdgcn_global_load_lds( \
    (const __attribute__((address_space(1))) void*)(gp),  \
    (__attribute__((address_space(3))) void*)(lp), 16, 0, 0)

// ---------------------------------------------------------------------------
// bf16 MFMA GEMM: C[M,N](bf16) = A[Mpad,K](bf16) @ Bt[N,K]^T + bias (+res)(+relu)
// 128x128 tile, BK=64 (K compile-time, fully unrolled), 4 waves (2x2).
// RES: 0 none, 1 fp32 residual, 2 bf16 residual.
// Bijective XCD swizzle (m204): consecutive work chunks -> same XCD L2.
// ---------------------------------------------------------------------------
template<int RELU, int RES, int K>
__global__ __launch_bounds__(256) void gemm_bf16(
    const u16* __restrict__ A, const u16* __restrict__ Bt,
    const float* __restrict__ bias, const void* __restrict__ res,
    u16* __restrict__ C, int M, int N)
{
    __shared__ u16 As[128][64];
    __shared__ u16 Bs[128][64];
    const int tid = threadIdx.x;
    const int wave = tid >> 6, lane = tid & 63;

    // XCD-aware bijective remap of linear block id
    const int gx = gridDim.x;
    const int nwg = gx * gridDim.y;
    const int orig = blockIdx.y * gx + blockIdx.x;
    const int q = nwg >> 3, r = nwg & 7;
    const int xcd = orig & 7, rank = orig >> 3;
    const int wg = (xcd < r ? xcd * (q + 1) : r * (q + 1) + (xcd - r) * q) + rank;
    const int m0 = (wg / gx) * 128, n0 = (wg % gx) * 128;

    const int wr = (wave >> 1) * 64, wc = (wave & 1) * 64;

    f32x4 acc[4][4] = {};

    const int srow = wave * 32 + (lane >> 3);
    const int scol = (lane & 7) * 8;

#pragma unroll
    for (int k0 = 0; k0 < K; k0 += 64) {
#pragma unroll
        for (int i = 0; i < 4; ++i)
            ASYNC16(A + (size_t)(m0 + srow + i * 8) * K + k0 + scol,
                    &As[wave * 32 + i * 8][0]);
#pragma unroll
        for (int i = 0; i < 4; ++i)
            ASYNC16(Bt + (size_t)(n0 + srow + i * 8) * K + k0 + scol,
                    &Bs[wave * 32 + i * 8][0]);
        __syncthreads();
#pragma unroll
        for (int kk = 0; kk < 64; kk += 32) {
            bf16x8 av[4], bv[4];
#pragma unroll
            for (int m = 0; m < 4; ++m)
                av[m] = *(const bf16x8*)&As[wr + m * 16 + (lane & 15)][kk + (lane >> 4) * 8];
#pragma unroll
            for (int n = 0; n < 4; ++n)
                bv[n] = *(const bf16x8*)&Bs[wc + n * 16 + (lane & 15)][kk + (lane >> 4) * 8];
#pragma unroll
            for (int m = 0; m < 4; ++m)
#pragma unroll
                for (int n = 0; n < 4; ++n)
                    acc[m][n] = __builtin_amdgcn_mfma_f32_16x16x32_bf16(
                        av[m], bv[n], acc[m][n], 0, 0, 0);
        }
        __syncthreads();
    }

    // epilogue: C/D layout col = lane&15, row = (lane>>4)*4 + reg  [m89-verified]
    const int col_l = lane & 15, rgrp = (lane >> 4) * 4;
#pragma unroll
    for (int m = 0; m < 4; ++m) {
#pragma unroll
        for (int rr = 0; rr < 4; ++rr) {
            const int row = m0 + wr + m * 16 + rgrp + rr;
            if (row >= M) continue;
#pragma unroll
            for (int n = 0; n < 4; ++n) {
                const int col = n0 + wc + n * 16 + col_l;
                float v = acc[m][n][rr] + bias[col];
                if (RES == 1) v += ((const float*)res)[(size_t)row * N + col];
                if (RES == 2) v += b2f(((const u16*)res)[(size_t)row * N + col]);
                if (RELU) v = fmaxf(v, 0.f);
                C[(size_t)row * N + col] = f2b(v);
            }
        }
    }
}

// ---------------------------------------------------------------------------
// Fused prep: x cast (blocks [0,6250)), weight transpose+cast ([6250,8042)),
// bias pack (block 8042)
// ---------------------------------------------------------------------------
__global__ __launch_bounds__(256) void prep_kernel(
    const float* __restrict__ x, u16* __restrict__ xb,
    const float* __restrict__ Wq, const float* __restrict__ Wk,
    const float* __restrict__ Wv, const float* __restrict__ Wo,
    const float* __restrict__ W1, const float* __restrict__ W2,
    u16* __restrict__ wqkvt, u16* __restrict__ wot,
    u16* __restrict__ w1t, u16* __restrict__ w2t,
    const float* __restrict__ bq, const float* __restrict__ bk,
    const float* __restrict__ bv, float* __restrict__ bqkv)
{
    const int b = blockIdx.x;
    if (b < 6250) {
        const size_t i = ((size_t)b * 256 + threadIdx.x) * 8;
        float4 a = *(const float4*)(x + i);
        float4 c = *(const float4*)(x + i + 4);
        u16 o[8] = {f2b(a.x), f2b(a.y), f2b(a.z), f2b(a.w),
                    f2b(c.x), f2b(c.y), f2b(c.z), f2b(c.w)};
        *(bf16x8*)(xb + i) = *(bf16x8*)o;
    } else if (b < 8042) {
        const int rr = b - 6250;
        const float* W; u16* o; int K, N, n;
        if (rr < 768)       { W = (rr < 256 ? Wq : (rr < 512 ? Wk : Wv));
                              n = rr & 255; o = wqkvt + (size_t)rr * 256; K = 256; N = 256; }
        else if (rr < 1024) { W = Wo; n = rr - 768;  o = wot + (size_t)n * 256; K = 256; N = 256; }
        else if (rr < 1536) { W = W1; n = rr - 1024; o = w1t + (size_t)n * 256; K = 256; N = 512; }
        else                { W = W2; n = rr - 1536; o = w2t + (size_t)n * 512; K = 512; N = 256; }
        for (int k = threadIdx.x; k < K; k += 256)
            o[k] = f2b(W[(size_t)k * N + n]);
    } else {
        const int t = threadIdx.x;
        bqkv[t] = bq[t]; bqkv[t + 256] = bk[t]; bqkv[t + 512] = bv[t];
    }
}

// ---------------------------------------------------------------------------
// s[n,h] = dot(Q[n,h], K[n,h]) / sqrt(32)   (Q,K inside packed QKV bf16)
// ---------------------------------------------------------------------------
__global__ __launch_bounds__(256) void score_kernel(
    const u16* __restrict__ QKV, float* __restrict__ s)
{
    const int t = blockIdx.x * 256 + threadIdx.x;
    if (t >= NN * NH) return;
    const int n = t >> 3, h = t & 7;
    const u16* qp = QKV + (size_t)n * DQKV + h * HD;
    const u16* kp = qp + DM;
    float acc = 0.f;
#pragma unroll
    for (int c = 0; c < HD; c += 8) {
        bf16x8 qa = *(const bf16x8*)(qp + c);
        bf16x8 ka = *(const bf16x8*)(kp + c);
#pragma unroll
        for (int j = 0; j < 8; ++j)
            acc += b2f((u16)qa[j]) * b2f((u16)ka[j]);
    }
    s[t] = acc * 0.17677669529663687f;
}

// ---------------------------------------------------------------------------
// CSR build
// ---------------------------------------------------------------------------
__global__ __launch_bounds__(256) void hist_kernel(
    const int* __restrict__ dst, int* __restrict__ counts, int E)
{
    const int e = blockIdx.x * 256 + threadIdx.x;
    if (e < E) atomicAdd(&counts[dst[e]], 1);
}

// single-block shuffle-based scan, 1024 threads = 16 waves
__global__ __launch_bounds__(1024) void scan_kernel(
    const int* __restrict__ counts, int* __restrict__ offs,
    int* __restrict__ cursor, int n)
{
    __shared__ int wsum[16];
    __shared__ int srun;
    const int tid = threadIdx.x, lane = tid & 63, wid = tid >> 6;
    if (tid == 0) srun = 0;
    for (int base = 0; base < n; base += 1024) {
        const int i = base + tid;
        const int v = (i < n) ? counts[i] : 0;
        int sc = v;
#pragma unroll
        for (int off = 1; off < 64; off <<= 1) {
            int t = __shfl_up(sc, off);
            if (lane >= off) sc += t;
        }
        if (lane == 63) wsum[wid] = sc;
        __syncthreads();
        if (tid < 16) {
            int w = wsum[tid];
#pragma unroll
            for (int off = 1; off < 16; off <<= 1) {
                int t = __shfl_up(w, off);
                if (tid >= off) w += t;
            }
            wsum[tid] = w;
        }
        __syncthreads();
        const int run = srun;
        const int excl = run + (wid ? wsum[wid - 1] : 0) + sc - v;
        if (i < n) { offs[i] = excl; cursor[i] = excl; }
        const int tot = wsum[15];
        __syncthreads();
        if (tid == 0) srun = run + tot;
    }
    if (tid == 0) offs[n] = srun;
}

__global__ __launch_bounds__(256) void fill_kernel(
    const int* __restrict__ src, const int* __restrict__ dst,
    int* __restrict__ cursor, int* __restrict__ csr_src, int E)
{
    const int e = blockIdx.x * 256 + threadIdx.x;
    if (e >= E) return;
    const int p = atomicAdd(&cursor[dst[e]], 1);
    csr_src[p] = src[e];
}

// ---------------------------------------------------------------------------
// SINGLE-PASS softmax-weighted V aggregation, one wave per node.
// Softmax is shift-invariant: acc = sum e^alpha * V, d = sum e^alpha, out=acc/d.
// |alpha| <= ~3 for this data (sigma~0.47); clamp at 30 guards fp32 overflow.
// ---------------------------------------------------------------------------
__global__ __launch_bounds__(256) void aggregate_kernel(
    const float* __restrict__ s, const u16* __restrict__ QKV,
    const int* __restrict__ offs, const int* __restrict__ srcs,
    u16* __restrict__ attn)
{
    const int n = (blockIdx.x * 256 + threadIdx.x) >> 6;
    const int lane = threadIdx.x & 63;
    if (n >= NN) return;
    const int base = offs[n];
    const int deg = offs[n + 1] - base;
    const int h0 = lane >> 3;
    const int f0 = lane * 4;
    const float snh = s[(size_t)n * 8 + h0];

    // self-loop
    float w = __expf(fminf(leaky(2.f * snh), 30.f));
    float d = w;
    bf16x4 vv = *(const bf16x4*)(QKV + (size_t)n * DQKV + 2 * DM + f0);
    float a0 = w * b2f((u16)vv[0]), a1 = w * b2f((u16)vv[1]);
    float a2 = w * b2f((u16)vv[2]), a3 = w * b2f((u16)vv[3]);

    for (int i = 0; i < deg; ++i) {
        const int sr = srcs[base + i];
        const float sv = s[(size_t)sr * 8 + h0];
        const float ww = __expf(fminf(leaky(snh + sv), 30.f));
        bf16x4 uv = *(const bf16x4*)(QKV + (size_t)sr * DQKV + 2 * DM + f0);
        d += ww;
        a0 += ww * b2f((u16)uv[0]); a1 += ww * b2f((u16)uv[1]);
        a2 += ww * b2f((u16)uv[2]); a3 += ww * b2f((u16)uv[3]);
    }
    const float rd = 1.f / d;
    u16 o[4] = {f2b(a0 * rd), f2b(a1 * rd), f2b(a2 * rd), f2b(a3 * rd)};
    *(bf16x4*)(attn + (size_t)n * DM + f0) = *(bf16x4*)o;
}

// ---------------------------------------------------------------------------
// BatchNorm stats (sum & sumsq per feature)
// ---------------------------------------------------------------------------
__global__ __launch_bounds__(256) void bn_stats_kernel(
    const u16* __restrict__ y, float* __restrict__ sums)
{
    const int f = threadIdx.x;
    float s = 0.f, q = 0.f;
    for (int r = blockIdx.x; r < NN; r += gridDim.x) {
        const float v = b2f(y[(size_t)r * DM + f]);
        s += v; q += v * v;
    }
    atomicAdd(&sums[f], s);
    atomicAdd(&sums[DM + f], q);
}

// y (bf16) = BN(y) in place; scale/shift computed inline from sums
__global__ __launch_bounds__(256) void apply_bf_kernel(
    u16* __restrict__ y, const float* __restrict__ sums,
    const float* __restrict__ g, const float* __restrict__ b)
{
    const size_t i = ((size_t)blockIdx.x * 256 + threadIdx.x) * 8;
    if (i >= (size_t)NN * DM) return;
    const int f0 = (int)(i & (DM - 1));
    const float invM = 1.f / (float)NN;
    bf16x8 v = *(bf16x8*)(y + i);
    u16 o[8];
#pragma unroll
    for (int j = 0; j < 8; ++j) {
        const int f = f0 + j;
        const float mean = sums[f] * invM;
        const float var = sums[DM + f] * invM - mean * mean;
        const float a = g[f] * rsqrtf(var + 1e-5f);
        o[j] = f2b(b2f((u16)v[j]) * a + (b[f] - mean * a));
    }
    *(bf16x8*)(y + i) = *(bf16x8*)o;
}

// out (fp32) = BN(z)
__global__ __launch_bounds__(256) void apply_out_kernel(
    const u16* __restrict__ z, const float* __restrict__ sums,
    const float* __restrict__ g, const float* __restrict__ b,
    float* __restrict__ out)
{
    const size_t i = ((size_t)blockIdx.x * 256 + threadIdx.x) * 8;
    if (i >= (size_t)NN * DM) return;
    const int f0 = (int)(i & (DM - 1));
    const float invM = 1.f / (float)NN;
    bf16x8 v = *(const bf16x8*)(z + i);
    float o[8];
#pragma unroll
    for (int j = 0; j < 8; ++j) {
        const int f = f0 + j;
        const float mean = sums[f] * invM;
        const float var = sums[DM + f] * invM - mean * mean;
        const float a = g[f] * rsqrtf(var + 1e-5f);
        o[j] = b2f((u16)v[j]) * a + (b[f] - mean * a);
    }
    *(float4*)(out + i)     = *(float4*)(o);
    *(float4*)(out + i + 4) = *(float4*)(o + 4);
}

// ---------------------------------------------------------------------------
extern "C" void kernel_launch(void* const* d_in, const int* in_sizes, int n_in,
                              void* d_out, int out_size, void* d_ws, size_t ws_size,
                              hipStream_t stream)
{
    const float* x   = (const float*)d_in[0];
    const int* eidx  = (const int*)d_in[1];
    const int E      = in_sizes[1] / 2;
    const int* esrc  = eidx;
    const int* edst  = eidx + E;
    const float* Wq = (const float*)d_in[2];  const float* bq = (const float*)d_in[3];
    const float* Wk = (const float*)d_in[4];  const float* bk = (const float*)d_in[5];
    const float* Wv = (const float*)d_in[6];  const float* bv = (const float*)d_in[7];
    const float* Wo = (const float*)d_in[8];  const float* bo = (const float*)d_in[9];
    const float* W1 = (const float*)d_in[10]; const float* b1 = (const float*)d_in[11];
    const float* W2 = (const float*)d_in[12]; const float* b2 = (const float*)d_in[13];
    const float* g1 = (const float*)d_in[14]; const float* be1 = (const float*)d_in[15];
    const float* g2 = (const float*)d_in[16]; const float* be2 = (const float*)d_in[17];
    float* out = (float*)d_out;

    // ---- workspace layout (bf16 = u16) ----
    u16* xb   = (u16*)d_ws;                       // [MP*DM]   xb -> y -> yn
    u16* qkv  = xb + (size_t)MP * DM;             // [MP*DQKV] QKV -> ff1
    u16* attn = qkv + (size_t)MP * DQKV;          // [MP*DM]   attn -> z
    float* sS = (float*)(attn + (size_t)MP * DM); // [NN*8]
    int* counts = (int*)(sS + (size_t)NN * NH);
    int* offs   = counts + NN;                    // NN+1
    int* cursor = offs + NN + 1;
    int* csr    = cursor + NN;                    // E
    uintptr_t p = (uintptr_t)(csr + E);
    p = (p + 15) & ~(uintptr_t)15;
    u16* wqkvt = (u16*)p;                         // [768*256]
    u16* wot   = wqkvt + 768 * 256;               // [256*256]
    u16* w1t   = wot + 256 * 256;                 // [512*256]
    u16* w2t   = w1t + 512 * 256;                 // [256*512]
    float* bqkv = (float*)(w2t + 256 * 512);      // [768]
    float* bnsum = bqkv + 768;                    // [512]

    const dim3 blk(256);
    const int elem_grid = (NN * DM / 8 + 255) / 256;

    // ---- prep (cast + weight packing + bias), CSR build ----
    hipMemsetAsync(counts, 0, sizeof(int) * NN, stream);
    prep_kernel<<<8043, blk, 0, stream>>>(x, xb, Wq, Wk, Wv, Wo, W1, W2,
                                          wqkvt, wot, w1t, w2t, bq, bk, bv, bqkv);
    hist_kernel<<<(E + 255) / 256, blk, 0, stream>>>(edst, counts, E);
    scan_kernel<<<1, 1024, 0, stream>>>(counts, offs, cursor, NN);
    fill_kernel<<<(E + 255) / 256, blk, 0, stream>>>(esrc, edst, cursor, csr, E);

    // ---- fused QKV projection ----
    gemm_bf16<0, 0, 256><<<dim3(DQKV / 128, MP / 128), blk, 0, stream>>>(
        xb, wqkvt, bqkv, nullptr, qkv, NN, DQKV);

    // ---- per-node scores ----
    score_kernel<<<(NN * NH + 255) / 256, blk, 0, stream>>>(qkv, sS);

    // ---- single-pass softmax + V aggregation ----
    aggregate_kernel<<<(NN + 3) / 4, blk, 0, stream>>>(sS, qkv, offs, csr, attn);

    // ---- O-projection + residual: y = x + attn @ Wo + bo (into xb region) ----
    gemm_bf16<0, 1, 256><<<dim3(DM / 128, MP / 128), blk, 0, stream>>>(
        attn, wot, bo, x, xb, NN, DM);

    // ---- BN1 stats -> apply in place (y -> yn) ----
    hipMemsetAsync(bnsum, 0, sizeof(float) * 2 * DM, stream);
    bn_stats_kernel<<<256, blk, 0, stream>>>(xb, bnsum);
    apply_bf_kernel<<<elem_grid, blk, 0, stream>>>(xb, bnsum, g1, be1);

    // ---- FF1: ff1 = relu(yn @ W1 + b1)  (into qkv region) ----
    gemm_bf16<1, 0, 256><<<dim3(DFF / 128, MP / 128), blk, 0, stream>>>(
        xb, w1t, b1, nullptr, qkv, NN, DFF);

    // ---- FF2 + residual: z = yn + ff1 @ W2 + b2  (into attn region) ----
    gemm_bf16<0, 2, 512><<<dim3(DM / 128, MP / 128), blk, 0, stream>>>(
        qkv, w2t, b2, xb, attn, NN, DM);

    // ---- BN2 stats -> out (fp32) ----
    hipMemsetAsync(bnsum, 0, sizeof(float) * 2 * DM, stream);
    bn_stats_kernel<<<256, blk, 0, stream>>>(attn, bnsum);
    apply_out_kernel<<<elem_grid, blk, 0, stream>>>(attn, bnsum, g2, be2, out);
}

// Round 4
// 461.962 us; speedup vs baseline: 2.7503x; 1.1818x over previous
//
#include <hip/hip_runtime.h>
#include <hip/hip_bf16.h>

#define NN 50000
#define MP 50048      // 391 * 128 (padded rows for tile staging)
#define DM 256
#define NH 8
#define HD 32
#define DFF 512

typedef unsigned short u16;
typedef __attribute__((ext_vector_type(8))) short bf16x8;
typedef __attribute__((ext_vector_type(4))) short bf16x4;
typedef __attribute__((ext_vector_type(4))) float f32x4;

__device__ __forceinline__ float leaky(float a) { return a > 0.f ? a : 0.2f * a; }

__device__ __forceinline__ float b2f(u16 s) {
    union { float f; unsigned u; } v; v.u = ((unsigned)s) << 16; return v.f;
}
__device__ __forceinline__ u16 f2b(float f) {
    union { float f; unsigned u; } v; v.f = f;
    unsigned r = v.u + 0x7FFFu + ((v.u >> 16) & 1u);
    return (u16)(r >> 16);
}

#define ASYNC16(gp, lp) __builtin_amdgcn_global_load_lds( \
    (const __attribute__((address_space(1))) void*)(gp),  \
    (__attribute__((address_space(3))) void*)(lp), 16, 0, 0)

// ---------------------------------------------------------------------------
// bf16 MFMA GEMM: 128x128 tile, BK=64 (K compile-time), 4 waves (2x2).
// RES: 0 none, 1 fp32 residual, 2 bf16 residual.
// MODE: 0 = plain C[M,N] store
//       1 = QKV split: cols<512 -> C (stride 512), cols>=512 -> Cv (stride 256)
//       2 = C store (N=256) + fused per-feature sum/sumsq into gsums[512]
// ---------------------------------------------------------------------------
template<int RELU, int RES, int K, int MODE>
__global__ __launch_bounds__(256) void gemm_bf16(
    const u16* __restrict__ A, const u16* __restrict__ Bt,
    const float* __restrict__ bias, const void* __restrict__ res,
    u16* __restrict__ C, u16* __restrict__ Cv, float* __restrict__ gsums,
    int M, int N)
{
    __shared__ u16 As[128][64];
    __shared__ u16 Bs[128][64];
    __shared__ float lsum[128], lsq[128];
    const int tid = threadIdx.x;
    const int wave = tid >> 6, lane = tid & 63;

    // XCD-aware bijective remap of linear block id (m204)
    const int gx = gridDim.x;
    const int nwg = gx * gridDim.y;
    const int orig = blockIdx.y * gx + blockIdx.x;
    const int q = nwg >> 3, r = nwg & 7;
    const int xcd = orig & 7, rank = orig >> 3;
    const int wg = (xcd < r ? xcd * (q + 1) : r * (q + 1) + (xcd - r) * q) + rank;
    const int m0 = (wg / gx) * 128, n0 = (wg % gx) * 128;

    const int wr = (wave >> 1) * 64, wc = (wave & 1) * 64;

    if (MODE == 2) {
        if (tid < 128) { lsum[tid] = 0.f; lsq[tid] = 0.f; }
    }

    f32x4 acc[4][4] = {};

    const int srow = wave * 32 + (lane >> 3);
    const int scol = (lane & 7) * 8;

#pragma unroll
    for (int k0 = 0; k0 < K; k0 += 64) {
#pragma unroll
        for (int i = 0; i < 4; ++i)
            ASYNC16(A + (size_t)(m0 + srow + i * 8) * K + k0 + scol,
                    &As[wave * 32 + i * 8][0]);
#pragma unroll
        for (int i = 0; i < 4; ++i)
            ASYNC16(Bt + (size_t)(n0 + srow + i * 8) * K + k0 + scol,
                    &Bs[wave * 32 + i * 8][0]);
        __syncthreads();
#pragma unroll
        for (int kk = 0; kk < 64; kk += 32) {
            bf16x8 av[4], bv[4];
#pragma unroll
            for (int m = 0; m < 4; ++m)
                av[m] = *(const bf16x8*)&As[wr + m * 16 + (lane & 15)][kk + (lane >> 4) * 8];
#pragma unroll
            for (int n = 0; n < 4; ++n)
                bv[n] = *(const bf16x8*)&Bs[wc + n * 16 + (lane & 15)][kk + (lane >> 4) * 8];
#pragma unroll
            for (int m = 0; m < 4; ++m)
#pragma unroll
                for (int n = 0; n < 4; ++n)
                    acc[m][n] = __builtin_amdgcn_mfma_f32_16x16x32_bf16(
                        av[m], bv[n], acc[m][n], 0, 0, 0);
        }
        __syncthreads();
    }

    // epilogue: C/D layout col = lane&15, row = (lane>>4)*4 + reg  [m89-verified]
    const int col_l = lane & 15, rgrp = (lane >> 4) * 4;
    float psum[4] = {0.f, 0.f, 0.f, 0.f}, psq[4] = {0.f, 0.f, 0.f, 0.f};
#pragma unroll
    for (int m = 0; m < 4; ++m) {
#pragma unroll
        for (int rr = 0; rr < 4; ++rr) {
            const int row = m0 + wr + m * 16 + rgrp + rr;
            if (row >= M) continue;
#pragma unroll
            for (int n = 0; n < 4; ++n) {
                const int col = n0 + wc + n * 16 + col_l;
                float v = acc[m][n][rr] + bias[col];
                if (RES == 1) v += ((const float*)res)[(size_t)row * N + col];
                if (RES == 2) v += b2f(((const u16*)res)[(size_t)row * N + col]);
                if (RELU) v = fmaxf(v, 0.f);
                if (MODE == 2) { psum[n] += v; psq[n] += v * v; }
                if (MODE == 1) {
                    if (col < 512) C[(size_t)row * 512 + col] = f2b(v);
                    else           Cv[(size_t)row * 256 + col - 512] = f2b(v);
                } else {
                    C[(size_t)row * N + col] = f2b(v);
                }
            }
        }
    }
    if (MODE == 2) {
        __syncthreads();
#pragma unroll
        for (int n = 0; n < 4; ++n) {
            atomicAdd(&lsum[wc + n * 16 + col_l], psum[n]);
            atomicAdd(&lsq[wc + n * 16 + col_l], psq[n]);
        }
        __syncthreads();
        if (tid < 128) {
            atomicAdd(&gsums[n0 + tid], lsum[tid]);
            atomicAdd(&gsums[DM + n0 + tid], lsq[tid]);
        }
    }
}

// ---------------------------------------------------------------------------
// Fused prep: x cast (blocks [0,6250)), weight transpose+cast ([6250,8042)),
// bias pack (block 8042)
// ---------------------------------------------------------------------------
__global__ __launch_bounds__(256) void prep_kernel(
    const float* __restrict__ x, u16* __restrict__ xb,
    const float* __restrict__ Wq, const float* __restrict__ Wk,
    const float* __restrict__ Wv, const float* __restrict__ Wo,
    const float* __restrict__ W1, const float* __restrict__ W2,
    u16* __restrict__ wqkvt, u16* __restrict__ wot,
    u16* __restrict__ w1t, u16* __restrict__ w2t,
    const float* __restrict__ bq, const float* __restrict__ bk,
    const float* __restrict__ bv, float* __restrict__ bqkv)
{
    const int b = blockIdx.x;
    if (b < 6250) {
        const size_t i = ((size_t)b * 256 + threadIdx.x) * 8;
        float4 a = *(const float4*)(x + i);
        float4 c = *(const float4*)(x + i + 4);
        u16 o[8] = {f2b(a.x), f2b(a.y), f2b(a.z), f2b(a.w),
                    f2b(c.x), f2b(c.y), f2b(c.z), f2b(c.w)};
        *(bf16x8*)(xb + i) = *(bf16x8*)o;
    } else if (b < 8042) {
        const int rr = b - 6250;
        const float* W; u16* o; int K, N, n;
        if (rr < 768)       { W = (rr < 256 ? Wq : (rr < 512 ? Wk : Wv));
                              n = rr & 255; o = wqkvt + (size_t)rr * 256; K = 256; N = 256; }
        else if (rr < 1024) { W = Wo; n = rr - 768;  o = wot + (size_t)n * 256; K = 256; N = 256; }
        else if (rr < 1536) { W = W1; n = rr - 1024; o = w1t + (size_t)n * 256; K = 256; N = 512; }
        else                { W = W2; n = rr - 1536; o = w2t + (size_t)n * 512; K = 512; N = 256; }
        for (int k = threadIdx.x; k < K; k += 256)
            o[k] = f2b(W[(size_t)k * N + n]);
    } else {
        const int t = threadIdx.x;
        bqkv[t] = bq[t]; bqkv[t + 256] = bk[t]; bqkv[t + 512] = bv[t];
    }
}

// ---------------------------------------------------------------------------
// s[n,h] = dot(Q[n,h], K[n,h]) / sqrt(32)   (QK buffer [MP][512]: Q | K)
// ---------------------------------------------------------------------------
__global__ __launch_bounds__(256) void score_kernel(
    const u16* __restrict__ QK, float* __restrict__ s)
{
    const int t = blockIdx.x * 256 + threadIdx.x;
    if (t >= NN * NH) return;
    const int n = t >> 3, h = t & 7;
    const u16* qp = QK + (size_t)n * 512 + h * HD;
    const u16* kp = qp + DM;
    float acc = 0.f;
#pragma unroll
    for (int c = 0; c < HD; c += 8) {
        bf16x8 qa = *(const bf16x8*)(qp + c);
        bf16x8 ka = *(const bf16x8*)(kp + c);
#pragma unroll
        for (int j = 0; j < 8; ++j)
            acc += b2f((u16)qa[j]) * b2f((u16)ka[j]);
    }
    s[t] = acc * 0.17677669529663687f;
}

// ---------------------------------------------------------------------------
// CSR build
// ---------------------------------------------------------------------------
__global__ __launch_bounds__(256) void hist_kernel(
    const int* __restrict__ dst, int* __restrict__ counts, int E)
{
    const int e = blockIdx.x * 256 + threadIdx.x;
    if (e < E) atomicAdd(&counts[dst[e]], 1);
}

__global__ __launch_bounds__(1024) void scan_kernel(
    const int* __restrict__ counts, int* __restrict__ offs,
    int* __restrict__ cursor, int n)
{
    __shared__ int wsum[16];
    __shared__ int srun;
    const int tid = threadIdx.x, lane = tid & 63, wid = tid >> 6;
    if (tid == 0) srun = 0;
    for (int base = 0; base < n; base += 1024) {
        const int i = base + tid;
        const int v = (i < n) ? counts[i] : 0;
        int sc = v;
#pragma unroll
        for (int off = 1; off < 64; off <<= 1) {
            int t = __shfl_up(sc, off);
            if (lane >= off) sc += t;
        }
        if (lane == 63) wsum[wid] = sc;
        __syncthreads();
        if (tid < 16) {
            int w = wsum[tid];
#pragma unroll
            for (int off = 1; off < 16; off <<= 1) {
                int t = __shfl_up(w, off);
                if (tid >= off) w += t;
            }
            wsum[tid] = w;
        }
        __syncthreads();
        const int run = srun;
        const int excl = run + (wid ? wsum[wid - 1] : 0) + sc - v;
        if (i < n) { offs[i] = excl; cursor[i] = excl; }
        const int tot = wsum[15];
        __syncthreads();
        if (tid == 0) srun = run + tot;
    }
    if (tid == 0) offs[n] = srun;
}

__global__ __launch_bounds__(256) void fill_kernel(
    const int* __restrict__ src, const int* __restrict__ dst,
    int* __restrict__ cursor, int* __restrict__ csr_src, int E)
{
    const int e = blockIdx.x * 256 + threadIdx.x;
    if (e >= E) return;
    const int p = atomicAdd(&cursor[dst[e]], 1);
    csr_src[p] = src[e];
}

// ---------------------------------------------------------------------------
// Single-pass softmax-weighted V aggregation, one wave per node, compact V.
// Unrolled x4: 4 independent V-row loads in flight per wave.
// ---------------------------------------------------------------------------
__global__ __launch_bounds__(256) void aggregate_kernel(
    const float* __restrict__ s, const u16* __restrict__ V,
    const int* __restrict__ offs, const int* __restrict__ srcs,
    u16* __restrict__ attn)
{
    const int n = (blockIdx.x * 256 + threadIdx.x) >> 6;
    const int lane = threadIdx.x & 63;
    if (n >= NN) return;
    const int base = offs[n];
    const int deg = offs[n + 1] - base;
    const int h0 = lane >> 3;
    const int f0 = lane * 4;
    const float snh = s[(size_t)n * 8 + h0];

    // self-loop
    float w = __expf(fminf(leaky(2.f * snh), 30.f));
    float d = w;
    bf16x4 vv = *(const bf16x4*)(V + (size_t)n * DM + f0);
    float a0 = w * b2f((u16)vv[0]), a1 = w * b2f((u16)vv[1]);
    float a2 = w * b2f((u16)vv[2]), a3 = w * b2f((u16)vv[3]);

    int i = 0;
    for (; i + 4 <= deg; i += 4) {
        const int sr0 = srcs[base + i + 0];
        const int sr1 = srcs[base + i + 1];
        const int sr2 = srcs[base + i + 2];
        const int sr3 = srcs[base + i + 3];
        const float sv0 = s[(size_t)sr0 * 8 + h0];
        const float sv1 = s[(size_t)sr1 * 8 + h0];
        const float sv2 = s[(size_t)sr2 * 8 + h0];
        const float sv3 = s[(size_t)sr3 * 8 + h0];
        bf16x4 u0 = *(const bf16x4*)(V + (size_t)sr0 * DM + f0);
        bf16x4 u1 = *(const bf16x4*)(V + (size_t)sr1 * DM + f0);
        bf16x4 u2 = *(const bf16x4*)(V + (size_t)sr2 * DM + f0);
        bf16x4 u3 = *(const bf16x4*)(V + (size_t)sr3 * DM + f0);
        const float w0 = __expf(fminf(leaky(snh + sv0), 30.f));
        const float w1 = __expf(fminf(leaky(snh + sv1), 30.f));
        const float w2 = __expf(fminf(leaky(snh + sv2), 30.f));
        const float w3 = __expf(fminf(leaky(snh + sv3), 30.f));
        d += w0 + w1 + w2 + w3;
        a0 += w0 * b2f((u16)u0[0]) + w1 * b2f((u16)u1[0])
            + w2 * b2f((u16)u2[0]) + w3 * b2f((u16)u3[0]);
        a1 += w0 * b2f((u16)u0[1]) + w1 * b2f((u16)u1[1])
            + w2 * b2f((u16)u2[1]) + w3 * b2f((u16)u3[1]);
        a2 += w0 * b2f((u16)u0[2]) + w1 * b2f((u16)u1[2])
            + w2 * b2f((u16)u2[2]) + w3 * b2f((u16)u3[2]);
        a3 += w0 * b2f((u16)u0[3]) + w1 * b2f((u16)u1[3])
            + w2 * b2f((u16)u2[3]) + w3 * b2f((u16)u3[3]);
    }
    for (; i < deg; ++i) {
        const int sr = srcs[base + i];
        const float sv = s[(size_t)sr * 8 + h0];
        const float ww = __expf(fminf(leaky(snh + sv), 30.f));
        bf16x4 uv = *(const bf16x4*)(V + (size_t)sr * DM + f0);
        d += ww;
        a0 += ww * b2f((u16)uv[0]); a1 += ww * b2f((u16)uv[1]);
        a2 += ww * b2f((u16)uv[2]); a3 += ww * b2f((u16)uv[3]);
    }
    const float rd = 1.f / d;
    u16 o[4] = {f2b(a0 * rd), f2b(a1 * rd), f2b(a2 * rd), f2b(a3 * rd)};
    *(bf16x4*)(attn + (size_t)n * DM + f0) = *(bf16x4*)o;
}

// ---------------------------------------------------------------------------
// BN apply (stats come pre-reduced from GEMM epilogues)
// ---------------------------------------------------------------------------
__global__ __launch_bounds__(256) void apply_bf_kernel(
    u16* __restrict__ y, const float* __restrict__ sums,
    const float* __restrict__ g, const float* __restrict__ b)
{
    const size_t i = ((size_t)blockIdx.x * 256 + threadIdx.x) * 8;
    if (i >= (size_t)NN * DM) return;
    const int f0 = (int)(i & (DM - 1));
    const float invM = 1.f / (float)NN;
    bf16x8 v = *(bf16x8*)(y + i);
    u16 o[8];
#pragma unroll
    for (int j = 0; j < 8; ++j) {
        const int f = f0 + j;
        const float mean = sums[f] * invM;
        const float var = sums[DM + f] * invM - mean * mean;
        const float a = g[f] * rsqrtf(var + 1e-5f);
        o[j] = f2b(b2f((u16)v[j]) * a + (b[f] - mean * a));
    }
    *(bf16x8*)(y + i) = *(bf16x8*)o;
}

__global__ __launch_bounds__(256) void apply_out_kernel(
    const u16* __restrict__ z, const float* __restrict__ sums,
    const float* __restrict__ g, const float* __restrict__ b,
    float* __restrict__ out)
{
    const size_t i = ((size_t)blockIdx.x * 256 + threadIdx.x) * 8;
    if (i >= (size_t)NN * DM) return;
    const int f0 = (int)(i & (DM - 1));
    const float invM = 1.f / (float)NN;
    bf16x8 v = *(const bf16x8*)(z + i);
    float o[8];
#pragma unroll
    for (int j = 0; j < 8; ++j) {
        const int f = f0 + j;
        const float mean = sums[f] * invM;
        const float var = sums[DM + f] * invM - mean * mean;
        const float a = g[f] * rsqrtf(var + 1e-5f);
        o[j] = b2f((u16)v[j]) * a + (b[f] - mean * a);
    }
    *(float4*)(out + i)     = *(float4*)(o);
    *(float4*)(out + i + 4) = *(float4*)(o + 4);
}

// ---------------------------------------------------------------------------
extern "C" void kernel_launch(void* const* d_in, const int* in_sizes, int n_in,
                              void* d_out, int out_size, void* d_ws, size_t ws_size,
                              hipStream_t stream)
{
    const float* x   = (const float*)d_in[0];
    const int* eidx  = (const int*)d_in[1];
    const int E      = in_sizes[1] / 2;
    const int* esrc  = eidx;
    const int* edst  = eidx + E;
    const float* Wq = (const float*)d_in[2];  const float* bq = (const float*)d_in[3];
    const float* Wk = (const float*)d_in[4];  const float* bk = (const float*)d_in[5];
    const float* Wv = (const float*)d_in[6];  const float* bv = (const float*)d_in[7];
    const float* Wo = (const float*)d_in[8];  const float* bo = (const float*)d_in[9];
    const float* W1 = (const float*)d_in[10]; const float* b1 = (const float*)d_in[11];
    const float* W2 = (const float*)d_in[12]; const float* b2 = (const float*)d_in[13];
    const float* g1 = (const float*)d_in[14]; const float* be1 = (const float*)d_in[15];
    const float* g2 = (const float*)d_in[16]; const float* be2 = (const float*)d_in[17];
    float* out = (float*)d_out;

    // ---- workspace layout (bf16 = u16) ----
    u16* xb  = (u16*)d_ws;                        // [MP*256]  x(bf16) -> y -> yn
    u16* qk  = xb + (size_t)MP * DM;              // [MP*512]  Q|K -> ff1
    u16* vb  = qk + (size_t)MP * 512;             // [MP*256]  compact V
    u16* attn = vb + (size_t)MP * DM;             // [MP*256]  attn -> z
    float* sS = (float*)(attn + (size_t)MP * DM); // [NN*8]
    int* counts = (int*)(sS + (size_t)NN * NH);
    int* offs   = counts + NN;                    // NN+1
    int* cursor = offs + NN + 1;
    int* csr    = cursor + NN;                    // E
    uintptr_t p = (uintptr_t)(csr + E);
    p = (p + 15) & ~(uintptr_t)15;
    u16* wqkvt = (u16*)p;                         // [768*256]
    u16* wot   = wqkvt + 768 * 256;               // [256*256]
    u16* w1t   = wot + 256 * 256;                 // [512*256]
    u16* w2t   = w1t + 512 * 256;                 // [256*512]
    float* bqkv  = (float*)(w2t + 256 * 512);     // [768]
    float* bnsum1 = bqkv + 768;                   // [512]
    float* bnsum2 = bnsum1 + 512;                 // [512]

    const dim3 blk(256);
    const int elem_grid = (NN * DM / 8 + 255) / 256;

    // ---- prep (cast + weight packing + bias), zero counters, CSR build ----
    hipMemsetAsync(counts, 0, sizeof(int) * NN, stream);
    hipMemsetAsync(bnsum1, 0, sizeof(float) * 1024, stream);
    prep_kernel<<<8043, blk, 0, stream>>>(x, xb, Wq, Wk, Wv, Wo, W1, W2,
                                          wqkvt, wot, w1t, w2t, bq, bk, bv, bqkv);
    hist_kernel<<<(E + 255) / 256, blk, 0, stream>>>(edst, counts, E);
    scan_kernel<<<1, 1024, 0, stream>>>(counts, offs, cursor, NN);
    fill_kernel<<<(E + 255) / 256, blk, 0, stream>>>(esrc, edst, cursor, csr, E);

    // ---- fused QKV projection (Q,K -> qk; V -> compact vb) ----
    gemm_bf16<0, 0, 256, 1><<<dim3(6, MP / 128), blk, 0, stream>>>(
        xb, wqkvt, bqkv, nullptr, qk, vb, nullptr, NN, 768);

    // ---- per-node scores ----
    score_kernel<<<(NN * NH + 255) / 256, blk, 0, stream>>>(qk, sS);

    // ---- single-pass softmax + V aggregation ----
    aggregate_kernel<<<(NN + 3) / 4, blk, 0, stream>>>(sS, vb, offs, csr, attn);

    // ---- O-projection + residual + fused BN1 stats: y = x + attn@Wo + bo ----
    gemm_bf16<0, 1, 256, 2><<<dim3(2, MP / 128), blk, 0, stream>>>(
        attn, wot, bo, x, xb, nullptr, bnsum1, NN, DM);

    // ---- BN1 apply in place (y -> yn) ----
    apply_bf_kernel<<<elem_grid, blk, 0, stream>>>(xb, bnsum1, g1, be1);

    // ---- FF1: ff1 = relu(yn @ W1 + b1)  (into qk region) ----
    gemm_bf16<1, 0, 256, 0><<<dim3(4, MP / 128), blk, 0, stream>>>(
        xb, w1t, b1, nullptr, qk, nullptr, nullptr, NN, DFF);

    // ---- FF2 + residual + fused BN2 stats: z = yn + ff1@W2 + b2 ----
    gemm_bf16<0, 2, 512, 2><<<dim3(2, MP / 128), blk, 0, stream>>>(
        qk, w2t, b2, xb, attn, nullptr, bnsum2, NN, DM);

    // ---- BN2 apply -> out (fp32) ----
    apply_out_kernel<<<elem_grid, blk, 0, stream>>>(attn, bnsum2, g2, be2, out);
}

// Round 5
// 409.678 us; speedup vs baseline: 3.1013x; 1.1276x over previous
//
#include <hip/hip_runtime.h>
#include <hip/hip_bf16.h>

#define NN 50000
#define MP 50048      // 391 * 128 (padded rows for tile staging)
#define DM 256
#define NH 8
#define HD 32
#define DFF 512

typedef unsigned short u16;
typedef __attribute__((ext_vector_type(8))) short bf16x8;
typedef __attribute__((ext_vector_type(4))) short bf16x4;
typedef __attribute__((ext_vector_type(4))) float f32x4;

__device__ __forceinline__ float leaky(float a) { return a > 0.f ? a : 0.2f * a; }

__device__ __forceinline__ float b2f(u16 s) {
    union { float f; unsigned u; } v; v.u = ((unsigned)s) << 16; return v.f;
}
__device__ __forceinline__ u16 f2b(float f) {
    union { float f; unsigned u; } v; v.f = f;
    unsigned r = v.u + 0x7FFFu + ((v.u >> 16) & 1u);
    return (u16)(r >> 16);
}

#define ASYNC16(gp, lp) __builtin_amdgcn_global_load_lds( \
    (const __attribute__((address_space(1))) void*)(gp),  \
    (__attribute__((address_space(3))) void*)(lp), 16, 0, 0)

// ---------------------------------------------------------------------------
// bf16 MFMA GEMM: 128x128 tile, BK=64 (K compile-time), 4 waves (2x2).
// LDS XOR-swizzle (both-sides: pre-swizzled global source + swizzled read,
// rule #21) kills the 16-way ds_read bank conflict.
// Epilogue stages C through LDS -> 16B/lane coalesced stores.
// RES: 0 none, 1 fp32 residual, 2 bf16 residual, 3 bf16 residual * ra + rb
// MODE: 0 plain store; 1 QKV split (cols<512 -> C stride 512, else Cv stride
//       256); 2 store + fused per-feature sum/sumsq into gsums[2*DM]
// ---------------------------------------------------------------------------
template<int RELU, int RES, int K, int MODE>
__global__ __launch_bounds__(256, 4) void gemm_bf16(
    const u16* __restrict__ A, const u16* __restrict__ Bt,
    const float* __restrict__ bias, const void* __restrict__ res,
    const float* __restrict__ ra, const float* __restrict__ rb,
    u16* __restrict__ C, u16* __restrict__ Cv, float* __restrict__ gsums,
    int M, int N)
{
    union SMu {
        struct { u16 As[128][64]; u16 Bs[128][64]; } t;
        u16 eps[128][136];
    };
    __shared__ __align__(16) SMu sm;
    __shared__ float lsum[128], lsq[128];

    const int tid = threadIdx.x;
    const int wave = tid >> 6, lane = tid & 63;

    // XCD-aware bijective remap of linear block id (m204)
    const int gx = gridDim.x;
    const int nwg = gx * gridDim.y;
    const int orig = blockIdx.y * gx + blockIdx.x;
    const int q = nwg >> 3, r = nwg & 7;
    const int xcd = orig & 7, rank = orig >> 3;
    const int wg = (xcd < r ? xcd * (q + 1) : r * (q + 1) + (xcd - r) * q) + rank;
    const int m0 = (wg / gx) * 128, n0 = (wg % gx) * 128;

    const int wr = (wave >> 1) * 64, wc = (wave & 1) * 64;

    if (MODE == 2 && tid < 128) { lsum[tid] = 0.f; lsq[tid] = 0.f; }

    f32x4 acc[4][4] = {};

    // staging: linear LDS dest, inverse-swizzled global source column
    const int srow = wave * 32 + (lane >> 3);
    const int scol = ((lane & 7) * 8) ^ (((lane >> 3) & 7) << 3);  // u16 units
    const int rx = (lane & 7) << 4;                                 // read XOR, bytes
    const char* asb = (const char*)&sm.t.As[0][0];
    const char* bsb = (const char*)&sm.t.Bs[0][0];

#pragma unroll
    for (int k0 = 0; k0 < K; k0 += 64) {
#pragma unroll
        for (int i = 0; i < 4; ++i)
            ASYNC16(A + (size_t)(m0 + srow + i * 8) * K + k0 + scol,
                    &sm.t.As[wave * 32 + i * 8][0]);
#pragma unroll
        for (int i = 0; i < 4; ++i)
            ASYNC16(Bt + (size_t)(n0 + srow + i * 8) * K + k0 + scol,
                    &sm.t.Bs[wave * 32 + i * 8][0]);
        __syncthreads();
#pragma unroll
        for (int kk = 0; kk < 64; kk += 32) {
            const int kb = (kk + (lane >> 4) * 8) * 2;  // byte col
            bf16x8 av[4], bv[4];
#pragma unroll
            for (int m = 0; m < 4; ++m) {
                const int rr_ = wr + m * 16 + (lane & 15);
                av[m] = *(const bf16x8*)(asb + rr_ * 128 + (kb ^ rx));
            }
#pragma unroll
            for (int n = 0; n < 4; ++n) {
                const int rr_ = wc + n * 16 + (lane & 15);
                bv[n] = *(const bf16x8*)(bsb + rr_ * 128 + (kb ^ rx));
            }
#pragma unroll
            for (int m = 0; m < 4; ++m)
#pragma unroll
                for (int n = 0; n < 4; ++n)
                    acc[m][n] = __builtin_amdgcn_mfma_f32_16x16x32_bf16(
                        av[m], bv[n], acc[m][n], 0, 0, 0);
        }
        __syncthreads();
    }

    // ---- epilogue phase 1: fragments -> LDS tile (C/D: col=lane&15,
    //      row=(lane>>4)*4+reg [m89-verified]) ----
    const int col_l = lane & 15, rgrp = (lane >> 4) * 4;
#pragma unroll
    for (int m = 0; m < 4; ++m)
#pragma unroll
        for (int rr2 = 0; rr2 < 4; ++rr2) {
            const int lr = wr + m * 16 + rgrp + rr2;
#pragma unroll
            for (int n = 0; n < 4; ++n)
                sm.eps[lr][wc + n * 16 + col_l] = f2b(acc[m][n][rr2]);
        }
    __syncthreads();

    // ---- epilogue phase 2: row-major read, bias/res/relu/sums, 16B stores ----
    const int tc = (tid & 15) * 8;
    float bb[8];
    *(float4*)(bb)     = *(const float4*)(bias + n0 + tc);
    *(float4*)(bb + 4) = *(const float4*)(bias + n0 + tc + 4);
    float ra8[8], rb8[8];
    if (RES == 3) {
        *(float4*)(ra8)     = *(const float4*)(ra + n0 + tc);
        *(float4*)(ra8 + 4) = *(const float4*)(ra + n0 + tc + 4);
        *(float4*)(rb8)     = *(const float4*)(rb + n0 + tc);
        *(float4*)(rb8 + 4) = *(const float4*)(rb + n0 + tc + 4);
    }
    float psum[8] = {}, psq[8] = {};
    u16* dstb; size_t dstride;
    if (MODE == 1) {
        if (n0 < 512) { dstb = C + n0; dstride = 512; }
        else          { dstb = Cv + (n0 - 512); dstride = 256; }
    } else { dstb = C + n0; dstride = (size_t)N; }

#pragma unroll
    for (int it = 0; it < 8; ++it) {
        const int tr = (tid >> 4) + it * 16;
        const int row = m0 + tr;
        if (row < M) {
            bf16x8 cv = *(const bf16x8*)((const char*)&sm.eps[0][0] + tr * 272 + tc * 2);
            float v[8];
#pragma unroll
            for (int j = 0; j < 8; ++j) v[j] = b2f((u16)cv[j]) + bb[j];
            if (RES == 1) {
                const float* rp = (const float*)res + (size_t)row * N + n0 + tc;
                float4 r0 = *(const float4*)(rp);
                float4 r1 = *(const float4*)(rp + 4);
                v[0] += r0.x; v[1] += r0.y; v[2] += r0.z; v[3] += r0.w;
                v[4] += r1.x; v[5] += r1.y; v[6] += r1.z; v[7] += r1.w;
            }
            if (RES == 2) {
                bf16x8 rv = *(const bf16x8*)((const u16*)res + (size_t)row * N + n0 + tc);
#pragma unroll
                for (int j = 0; j < 8; ++j) v[j] += b2f((u16)rv[j]);
            }
            if (RES == 3) {
                bf16x8 rv = *(const bf16x8*)((const u16*)res + (size_t)row * N + n0 + tc);
#pragma unroll
                for (int j = 0; j < 8; ++j) v[j] += b2f((u16)rv[j]) * ra8[j] + rb8[j];
            }
            if (RELU) {
#pragma unroll
                for (int j = 0; j < 8; ++j) v[j] = fmaxf(v[j], 0.f);
            }
            if (MODE == 2) {
#pragma unroll
                for (int j = 0; j < 8; ++j) { psum[j] += v[j]; psq[j] += v[j] * v[j]; }
            }
            u16 o[8];
#pragma unroll
            for (int j = 0; j < 8; ++j) o[j] = f2b(v[j]);
            *(bf16x8*)(dstb + (size_t)row * dstride + tc) = *(bf16x8*)o;
        }
    }

    if (MODE == 2) {
#pragma unroll
        for (int j = 0; j < 8; ++j) {
            atomicAdd(&lsum[tc + j], psum[j]);
            atomicAdd(&lsq[tc + j], psq[j]);
        }
        __syncthreads();
        if (tid < 128) {
            atomicAdd(&gsums[n0 + tid], lsum[tid]);
            atomicAdd(&gsums[DM + n0 + tid], lsq[tid]);
        }
    }
}

// ---------------------------------------------------------------------------
// Fused prep: x cast (blocks [0,6250)), weight transpose+cast ([6250,8042)),
// bias pack (block 8042)
// ---------------------------------------------------------------------------
__global__ __launch_bounds__(256) void prep_kernel(
    const float* __restrict__ x, u16* __restrict__ xb,
    const float* __restrict__ Wq, const float* __restrict__ Wk,
    const float* __restrict__ Wv, const float* __restrict__ Wo,
    const float* __restrict__ W1, const float* __restrict__ W2,
    u16* __restrict__ wqkvt, u16* __restrict__ wot,
    u16* __restrict__ w1t, u16* __restrict__ w2t,
    const float* __restrict__ bq, const float* __restrict__ bk,
    const float* __restrict__ bv, float* __restrict__ bqkv)
{
    const int b = blockIdx.x;
    if (b < 6250) {
        const size_t i = ((size_t)b * 256 + threadIdx.x) * 8;
        float4 a = *(const float4*)(x + i);
        float4 c = *(const float4*)(x + i + 4);
        u16 o[8] = {f2b(a.x), f2b(a.y), f2b(a.z), f2b(a.w),
                    f2b(c.x), f2b(c.y), f2b(c.z), f2b(c.w)};
        *(bf16x8*)(xb + i) = *(bf16x8*)o;
    } else if (b < 8042) {
        const int rr = b - 6250;
        const float* W; u16* o; int K, N, n;
        if (rr < 768)       { W = (rr < 256 ? Wq : (rr < 512 ? Wk : Wv));
                              n = rr & 255; o = wqkvt + (size_t)rr * 256; K = 256; N = 256; }
        else if (rr < 1024) { W = Wo; n = rr - 768;  o = wot + (size_t)n * 256; K = 256; N = 256; }
        else if (rr < 1536) { W = W1; n = rr - 1024; o = w1t + (size_t)n * 256; K = 256; N = 512; }
        else                { W = W2; n = rr - 1536; o = w2t + (size_t)n * 512; K = 512; N = 256; }
        for (int k = threadIdx.x; k < K; k += 256)
            o[k] = f2b(W[(size_t)k * N + n]);
    } else {
        const int t = threadIdx.x;
        bqkv[t] = bq[t]; bqkv[t + 256] = bk[t]; bqkv[t + 512] = bv[t];
    }
}

// ---------------------------------------------------------------------------
// BN1 fold: a,c from stats; w1t[n][k]*=a[k]; b1p = b1 + c @ W1; save a,c
// blocks 0..63: scale w1t (8 rows each); blocks 64,65: b1p halves
// ---------------------------------------------------------------------------
__global__ __launch_bounds__(256) void bnfold_kernel(
    const float* __restrict__ sums, const float* __restrict__ g,
    const float* __restrict__ be, u16* __restrict__ w1t,
    const float* __restrict__ W1, const float* __restrict__ b1,
    float* __restrict__ b1p, float* __restrict__ affa, float* __restrict__ affc)
{
    const int blk = blockIdx.x;
    const int k = threadIdx.x;
    const float invM = 1.f / (float)NN;
    const float mean = sums[k] * invM;
    const float var = sums[DM + k] * invM - mean * mean;
    const float a = g[k] * rsqrtf(var + 1e-5f);
    const float c = be[k] - mean * a;
    if (blk < 64) {
#pragma unroll
        for (int j = 0; j < 8; ++j) {
            u16* pp = w1t + (size_t)(blk * 8 + j) * 256 + k;
            *pp = f2b(b2f(*pp) * a);
        }
    } else {
        __shared__ float cs[256];
        cs[k] = c;
        if (blk == 64) { affa[k] = a; affc[k] = c; }
        __syncthreads();
        const int n = (blk - 64) * 256 + k;
        float acc = b1[n];
        for (int kk = 0; kk < 256; ++kk)
            acc += cs[kk] * W1[(size_t)kk * 512 + n];
        b1p[n] = acc;
    }
}

// ---------------------------------------------------------------------------
// s[n,h] = dot(Q[n,h], K[n,h]) / sqrt(32)   (QK buffer [MP][512]: Q | K)
// ---------------------------------------------------------------------------
__global__ __launch_bounds__(256) void score_kernel(
    const u16* __restrict__ QK, float* __restrict__ s)
{
    const int t = blockIdx.x * 256 + threadIdx.x;
    if (t >= NN * NH) return;
    const int n = t >> 3, h = t & 7;
    const u16* qp = QK + (size_t)n * 512 + h * HD;
    const u16* kp = qp + DM;
    float acc = 0.f;
#pragma unroll
    for (int c = 0; c < HD; c += 8) {
        bf16x8 qa = *(const bf16x8*)(qp + c);
        bf16x8 ka = *(const bf16x8*)(kp + c);
#pragma unroll
        for (int j = 0; j < 8; ++j)
            acc += b2f((u16)qa[j]) * b2f((u16)ka[j]);
    }
    s[t] = acc * 0.17677669529663687f;
}

// ---------------------------------------------------------------------------
// CSR build
// ---------------------------------------------------------------------------
__global__ __launch_bounds__(256) void hist_kernel(
    const int* __restrict__ dst, int* __restrict__ counts, int E)
{
    const int e = blockIdx.x * 256 + threadIdx.x;
    if (e < E) atomicAdd(&counts[dst[e]], 1);
}

__global__ __launch_bounds__(1024) void scan_kernel(
    const int* __restrict__ counts, int* __restrict__ offs,
    int* __restrict__ cursor, int n)
{
    __shared__ int wsum[16];
    __shared__ int srun;
    const int tid = threadIdx.x, lane = tid & 63, wid = tid >> 6;
    if (tid == 0) srun = 0;
    for (int base = 0; base < n; base += 1024) {
        const int i = base + tid;
        const int v = (i < n) ? counts[i] : 0;
        int sc = v;
#pragma unroll
        for (int off = 1; off < 64; off <<= 1) {
            int t = __shfl_up(sc, off);
            if (lane >= off) sc += t;
        }
        if (lane == 63) wsum[wid] = sc;
        __syncthreads();
        if (tid < 16) {
            int w = wsum[tid];
#pragma unroll
            for (int off = 1; off < 16; off <<= 1) {
                int t = __shfl_up(w, off);
                if (tid >= off) w += t;
            }
            wsum[tid] = w;
        }
        __syncthreads();
        const int run = srun;
        const int excl = run + (wid ? wsum[wid - 1] : 0) + sc - v;
        if (i < n) { offs[i] = excl; cursor[i] = excl; }
        const int tot = wsum[15];
        __syncthreads();
        if (tid == 0) srun = run + tot;
    }
    if (tid == 0) offs[n] = srun;
}

__global__ __launch_bounds__(256) void fill_kernel(
    const int* __restrict__ src, const int* __restrict__ dst,
    int* __restrict__ cursor, int* __restrict__ csr_src, int E)
{
    const int e = blockIdx.x * 256 + threadIdx.x;
    if (e >= E) return;
    const int p = atomicAdd(&cursor[dst[e]], 1);
    csr_src[p] = src[e];
}

// ---------------------------------------------------------------------------
// Single-pass softmax-weighted V aggregation, one wave per node, compact V.
// ---------------------------------------------------------------------------
__global__ __launch_bounds__(256) void aggregate_kernel(
    const float* __restrict__ s, const u16* __restrict__ V,
    const int* __restrict__ offs, const int* __restrict__ srcs,
    u16* __restrict__ attn)
{
    const int n = (blockIdx.x * 256 + threadIdx.x) >> 6;
    const int lane = threadIdx.x & 63;
    if (n >= NN) return;
    const int base = offs[n];
    const int deg = offs[n + 1] - base;
    const int h0 = lane >> 3;
    const int f0 = lane * 4;
    const float snh = s[(size_t)n * 8 + h0];

    float w = __expf(fminf(leaky(2.f * snh), 30.f));
    float d = w;
    bf16x4 vv = *(const bf16x4*)(V + (size_t)n * DM + f0);
    float a0 = w * b2f((u16)vv[0]), a1 = w * b2f((u16)vv[1]);
    float a2 = w * b2f((u16)vv[2]), a3 = w * b2f((u16)vv[3]);

    int i = 0;
    for (; i + 4 <= deg; i += 4) {
        const int sr0 = srcs[base + i + 0];
        const int sr1 = srcs[base + i + 1];
        const int sr2 = srcs[base + i + 2];
        const int sr3 = srcs[base + i + 3];
        const float sv0 = s[(size_t)sr0 * 8 + h0];
        const float sv1 = s[(size_t)sr1 * 8 + h0];
        const float sv2 = s[(size_t)sr2 * 8 + h0];
        const float sv3 = s[(size_t)sr3 * 8 + h0];
        bf16x4 u0 = *(const bf16x4*)(V + (size_t)sr0 * DM + f0);
        bf16x4 u1 = *(const bf16x4*)(V + (size_t)sr1 * DM + f0);
        bf16x4 u2 = *(const bf16x4*)(V + (size_t)sr2 * DM + f0);
        bf16x4 u3 = *(const bf16x4*)(V + (size_t)sr3 * DM + f0);
        const float w0 = __expf(fminf(leaky(snh + sv0), 30.f));
        const float w1 = __expf(fminf(leaky(snh + sv1), 30.f));
        const float w2 = __expf(fminf(leaky(snh + sv2), 30.f));
        const float w3 = __expf(fminf(leaky(snh + sv3), 30.f));
        d += w0 + w1 + w2 + w3;
        a0 += w0 * b2f((u16)u0[0]) + w1 * b2f((u16)u1[0])
            + w2 * b2f((u16)u2[0]) + w3 * b2f((u16)u3[0]);
        a1 += w0 * b2f((u16)u0[1]) + w1 * b2f((u16)u1[1])
            + w2 * b2f((u16)u2[1]) + w3 * b2f((u16)u3[1]);
        a2 += w0 * b2f((u16)u0[2]) + w1 * b2f((u16)u1[2])
            + w2 * b2f((u16)u2[2]) + w3 * b2f((u16)u3[2]);
        a3 += w0 * b2f((u16)u0[3]) + w1 * b2f((u16)u1[3])
            + w2 * b2f((u16)u2[3]) + w3 * b2f((u16)u3[3]);
    }
    for (; i < deg; ++i) {
        const int sr = srcs[base + i];
        const float sv = s[(size_t)sr * 8 + h0];
        const float ww = __expf(fminf(leaky(snh + sv), 30.f));
        bf16x4 uv = *(const bf16x4*)(V + (size_t)sr * DM + f0);
        d += ww;
        a0 += ww * b2f((u16)uv[0]); a1 += ww * b2f((u16)uv[1]);
        a2 += ww * b2f((u16)uv[2]); a3 += ww * b2f((u16)uv[3]);
    }
    const float rd = 1.f / d;
    u16 o[4] = {f2b(a0 * rd), f2b(a1 * rd), f2b(a2 * rd), f2b(a3 * rd)};
    *(bf16x4*)(attn + (size_t)n * DM + f0) = *(bf16x4*)o;
}

// ---------------------------------------------------------------------------
// BN2 apply -> fp32 out (stats pre-reduced by GEMM epilogue)
// ---------------------------------------------------------------------------
__global__ __launch_bounds__(256) void apply_out_kernel(
    const u16* __restrict__ z, const float* __restrict__ sums,
    const float* __restrict__ g, const float* __restrict__ b,
    float* __restrict__ out)
{
    const size_t i = ((size_t)blockIdx.x * 256 + threadIdx.x) * 8;
    if (i >= (size_t)NN * DM) return;
    const int f0 = (int)(i & (DM - 1));
    const float invM = 1.f / (float)NN;
    bf16x8 v = *(const bf16x8*)(z + i);
    float o[8];
#pragma unroll
    for (int j = 0; j < 8; ++j) {
        const int f = f0 + j;
        const float mean = sums[f] * invM;
        const float var = sums[DM + f] * invM - mean * mean;
        const float a = g[f] * rsqrtf(var + 1e-5f);
        o[j] = b2f((u16)v[j]) * a + (b[f] - mean * a);
    }
    *(float4*)(out + i)     = *(float4*)(o);
    *(float4*)(out + i + 4) = *(float4*)(o + 4);
}

// ---------------------------------------------------------------------------
extern "C" void kernel_launch(void* const* d_in, const int* in_sizes, int n_in,
                              void* d_out, int out_size, void* d_ws, size_t ws_size,
                              hipStream_t stream)
{
    const float* x   = (const float*)d_in[0];
    const int* eidx  = (const int*)d_in[1];
    const int E      = in_sizes[1] / 2;
    const int* esrc  = eidx;
    const int* edst  = eidx + E;
    const float* Wq = (const float*)d_in[2];  const float* bq = (const float*)d_in[3];
    const float* Wk = (const float*)d_in[4];  const float* bk = (const float*)d_in[5];
    const float* Wv = (const float*)d_in[6];  const float* bv = (const float*)d_in[7];
    const float* Wo = (const float*)d_in[8];  const float* bo = (const float*)d_in[9];
    const float* W1 = (const float*)d_in[10]; const float* b1 = (const float*)d_in[11];
    const float* W2 = (const float*)d_in[12]; const float* b2 = (const float*)d_in[13];
    const float* g1 = (const float*)d_in[14]; const float* be1 = (const float*)d_in[15];
    const float* g2 = (const float*)d_in[16]; const float* be2 = (const float*)d_in[17];
    float* out = (float*)d_out;

    // ---- workspace layout (bf16 = u16) ----
    u16* xb  = (u16*)d_ws;                        // [MP*256]  x(bf16) -> y
    u16* qk  = xb + (size_t)MP * DM;              // [MP*512]  Q|K -> ff1
    u16* vb  = qk + (size_t)MP * 512;             // [MP*256]  compact V
    u16* attn = vb + (size_t)MP * DM;             // [MP*256]  attn -> z
    float* sS = (float*)(attn + (size_t)MP * DM); // [NN*8]
    int* counts = (int*)(sS + (size_t)NN * NH);
    int* offs   = counts + NN;                    // NN+1
    int* cursor = offs + NN + 1;
    int* csr    = cursor + NN;                    // E
    uintptr_t p = (uintptr_t)(csr + E);
    p = (p + 15) & ~(uintptr_t)15;
    u16* wqkvt = (u16*)p;                         // [768*256]
    u16* wot   = wqkvt + 768 * 256;               // [256*256]
    u16* w1t   = wot + 256 * 256;                 // [512*256]
    u16* w2t   = w1t + 512 * 256;                 // [256*512]
    float* bqkv   = (float*)(w2t + 256 * 512);    // [768]
    float* bnsum1 = bqkv + 768;                   // [512]
    float* bnsum2 = bnsum1 + 512;                 // [512]
    float* b1p    = bnsum2 + 512;                 // [512]
    float* affa   = b1p + 512;                    // [256]
    float* affc   = affa + 256;                   // [256]

    const dim3 blk(256);
    const int elem_grid = (NN * DM / 8 + 255) / 256;

    // ---- prep (cast + weight packing + bias), zero counters, CSR build ----
    hipMemsetAsync(counts, 0, sizeof(int) * NN, stream);
    hipMemsetAsync(bnsum1, 0, sizeof(float) * 1024, stream);
    prep_kernel<<<8043, blk, 0, stream>>>(x, xb, Wq, Wk, Wv, Wo, W1, W2,
                                          wqkvt, wot, w1t, w2t, bq, bk, bv, bqkv);
    hist_kernel<<<(E + 255) / 256, blk, 0, stream>>>(edst, counts, E);
    scan_kernel<<<1, 1024, 0, stream>>>(counts, offs, cursor, NN);
    fill_kernel<<<(E + 255) / 256, blk, 0, stream>>>(esrc, edst, cursor, csr, E);

    // ---- fused QKV projection (Q,K -> qk; V -> compact vb) ----
    gemm_bf16<0, 0, 256, 1><<<dim3(6, MP / 128), blk, 0, stream>>>(
        xb, wqkvt, bqkv, nullptr, nullptr, nullptr, qk, vb, nullptr, NN, 768);

    // ---- per-node scores ----
    score_kernel<<<(NN * NH + 255) / 256, blk, 0, stream>>>(qk, sS);

    // ---- single-pass softmax + V aggregation ----
    aggregate_kernel<<<(NN + 3) / 4, blk, 0, stream>>>(sS, vb, offs, csr, attn);

    // ---- O-projection + residual + fused BN1 stats: y = x + attn@Wo + bo ----
    gemm_bf16<0, 1, 256, 2><<<dim3(2, MP / 128), blk, 0, stream>>>(
        attn, wot, bo, x, nullptr, nullptr, xb, nullptr, bnsum1, NN, DM);

    // ---- fold BN1 into W1/b1 (w1t *= a, b1p = b1 + c@W1; save a,c) ----
    bnfold_kernel<<<66, blk, 0, stream>>>(bnsum1, g1, be1, w1t, W1, b1,
                                          b1p, affa, affc);

    // ---- FF1: ff1 = relu(y @ (aW1) + b1')  (into qk region) ----
    gemm_bf16<1, 0, 256, 0><<<dim3(4, MP / 128), blk, 0, stream>>>(
        xb, w1t, b1p, nullptr, nullptr, nullptr, qk, nullptr, nullptr, NN, DFF);

    // ---- FF2 + affine residual + fused BN2 stats: z = (a*y+c) + ff1@W2 + b2 ----
    gemm_bf16<0, 3, 512, 2><<<dim3(2, MP / 128), blk, 0, stream>>>(
        qk, w2t, b2, xb, affa, affc, attn, nullptr, bnsum2, NN, DM);

    // ---- BN2 apply -> out (fp32) ----
    apply_out_kernel<<<elem_grid, blk, 0, stream>>>(attn, bnsum2, g2, be2, out);
}

// Round 6
// 397.519 us; speedup vs baseline: 3.1962x; 1.0306x over previous
//
#include <hip/hip_runtime.h>
#include <hip/hip_bf16.h>

#define NN 50000
#define MP 50048      // 391 * 128 (padded rows for tile staging)
#define DM 256
#define NH 8
#define HD 32
#define DFF 512

typedef unsigned short u16;
typedef __attribute__((ext_vector_type(8))) short bf16x8;
typedef __attribute__((ext_vector_type(4))) short bf16x4;
typedef __attribute__((ext_vector_type(4))) float f32x4;

__device__ __forceinline__ float leaky(float a) { return a > 0.f ? a : 0.2f * a; }

__device__ __forceinline__ float b2f(u16 s) {
    union { float f; unsigned u; } v; v.u = ((unsigned)s) << 16; return v.f;
}
__device__ __forceinline__ u16 f2b(float f) {
    union { float f; unsigned u; } v; v.f = f;
    unsigned r = v.u + 0x7FFFu + ((v.u >> 16) & 1u);
    return (u16)(r >> 16);
}

#define ASYNC16(gp, lp) __builtin_amdgcn_global_load_lds( \
    (const __attribute__((address_space(1))) void*)(gp),  \
    (__attribute__((address_space(3))) void*)(lp), 16, 0, 0)

// ---------------------------------------------------------------------------
// bf16 MFMA GEMM: 128x128 tile, BK=64 (K compile-time), 4 waves (2x2).
// 2-phase double-buffered pipeline: issue next-tile global_load_lds BEFORE
// computing current tile; __syncthreads at iteration end both drains the
// prefetch (vmcnt0) and separates buffer reuse. Stage latency hides under
// the ds_read+MFMA phase.
// LDS XOR-swizzle (both-sides, rule #21) for conflict-free ds_read_b128.
// Epilogue staged through LDS -> 16B/lane coalesced stores.
// RES: 0 none, 1 fp32 residual, 2 bf16 residual, 3 bf16 residual * ra + rb
// MODE: 0 plain store; 1 QKV split (cols<512 -> C stride 512, else Cv stride
//       256); 2 store + fused per-feature sum/sumsq into gsums[2*DM]
// ---------------------------------------------------------------------------
template<int RELU, int RES, int K, int MODE>
__global__ __launch_bounds__(256, 2) void gemm_bf16(
    const u16* __restrict__ A, const u16* __restrict__ Bt,
    const float* __restrict__ bias, const void* __restrict__ res,
    const float* __restrict__ ra, const float* __restrict__ rb,
    u16* __restrict__ C, u16* __restrict__ Cv, float* __restrict__ gsums,
    int M, int N)
{
    union SMu {
        struct { u16 As[2][128][64]; u16 Bs[2][128][64]; } t;          // 65536 B
        struct { u16 eps[128][136]; float lsum[128]; float lsq[128]; } e;  // 35840 B
    };
    __shared__ __align__(16) SMu sm;

    const int tid = threadIdx.x;
    const int wave = tid >> 6, lane = tid & 63;

    // XCD-aware bijective remap of linear block id (m204)
    const int gx = gridDim.x;
    const int nwg = gx * gridDim.y;
    const int orig = blockIdx.y * gx + blockIdx.x;
    const int q = nwg >> 3, r = nwg & 7;
    const int xcd = orig & 7, rank = orig >> 3;
    const int wg = (xcd < r ? xcd * (q + 1) : r * (q + 1) + (xcd - r) * q) + rank;
    const int m0 = (wg / gx) * 128, n0 = (wg % gx) * 128;

    const int wr = (wave >> 1) * 64, wc = (wave & 1) * 64;

    f32x4 acc[4][4] = {};

    // staging: linear LDS dest, inverse-swizzled global source column
    const int srow = wave * 32 + (lane >> 3);
    const int scol = ((lane & 7) * 8) ^ (((lane >> 3) & 7) << 3);  // u16 units
    const int rx = (lane & 7) << 4;                                 // read XOR, bytes

    // prologue: stage tile 0 into buffer 0
#pragma unroll
    for (int i = 0; i < 4; ++i)
        ASYNC16(A + (size_t)(m0 + srow + i * 8) * K + scol,
                &sm.t.As[0][wave * 32 + i * 8][0]);
#pragma unroll
    for (int i = 0; i < 4; ++i)
        ASYNC16(Bt + (size_t)(n0 + srow + i * 8) * K + scol,
                &sm.t.Bs[0][wave * 32 + i * 8][0]);
    __syncthreads();

    const int nt = K / 64;
#pragma unroll
    for (int t = 0; t < nt; ++t) {
        const int cur = t & 1;
        if (t + 1 < nt) {
            const int k1 = (t + 1) * 64;
            const int nb = (t + 1) & 1;
#pragma unroll
            for (int i = 0; i < 4; ++i)
                ASYNC16(A + (size_t)(m0 + srow + i * 8) * K + k1 + scol,
                        &sm.t.As[nb][wave * 32 + i * 8][0]);
#pragma unroll
            for (int i = 0; i < 4; ++i)
                ASYNC16(Bt + (size_t)(n0 + srow + i * 8) * K + k1 + scol,
                        &sm.t.Bs[nb][wave * 32 + i * 8][0]);
        }
        const char* asb = (const char*)&sm.t.As[cur][0][0];
        const char* bsb = (const char*)&sm.t.Bs[cur][0][0];
#pragma unroll
        for (int kk = 0; kk < 64; kk += 32) {
            const int kb = (kk + (lane >> 4) * 8) * 2;  // byte col
            bf16x8 av[4], bv[4];
#pragma unroll
            for (int m = 0; m < 4; ++m) {
                const int rr_ = wr + m * 16 + (lane & 15);
                av[m] = *(const bf16x8*)(asb + rr_ * 128 + (kb ^ rx));
            }
#pragma unroll
            for (int n = 0; n < 4; ++n) {
                const int rr_ = wc + n * 16 + (lane & 15);
                bv[n] = *(const bf16x8*)(bsb + rr_ * 128 + (kb ^ rx));
            }
#pragma unroll
            for (int m = 0; m < 4; ++m)
#pragma unroll
                for (int n = 0; n < 4; ++n)
                    acc[m][n] = __builtin_amdgcn_mfma_f32_16x16x32_bf16(
                        av[m], bv[n], acc[m][n], 0, 0, 0);
        }
        __syncthreads();  // drains prefetch (vmcnt0) + separates buffer reuse
    }

    // ---- epilogue phase 1: fragments -> LDS tile (C/D: col=lane&15,
    //      row=(lane>>4)*4+reg [m89-verified]) ----
    const int col_l = lane & 15, rgrp = (lane >> 4) * 4;
#pragma unroll
    for (int m = 0; m < 4; ++m)
#pragma unroll
        for (int rr2 = 0; rr2 < 4; ++rr2) {
            const int lr = wr + m * 16 + rgrp + rr2;
#pragma unroll
            for (int n = 0; n < 4; ++n)
                sm.e.eps[lr][wc + n * 16 + col_l] = f2b(acc[m][n][rr2]);
        }
    __syncthreads();
    if (MODE == 2) {
        if (tid < 128) { sm.e.lsum[tid] = 0.f; sm.e.lsq[tid] = 0.f; }
        __syncthreads();
    }

    // ---- epilogue phase 2: row-major read, bias/res/relu/sums, 16B stores ----
    const int tc = (tid & 15) * 8;
    float bb[8];
    *(float4*)(bb)     = *(const float4*)(bias + n0 + tc);
    *(float4*)(bb + 4) = *(const float4*)(bias + n0 + tc + 4);
    float ra8[8], rb8[8];
    if (RES == 3) {
        *(float4*)(ra8)     = *(const float4*)(ra + n0 + tc);
        *(float4*)(ra8 + 4) = *(const float4*)(ra + n0 + tc + 4);
        *(float4*)(rb8)     = *(const float4*)(rb + n0 + tc);
        *(float4*)(rb8 + 4) = *(const float4*)(rb + n0 + tc + 4);
    }
    float psum[8] = {}, psq[8] = {};
    u16* dstb; size_t dstride;
    if (MODE == 1) {
        if (n0 < 512) { dstb = C + n0; dstride = 512; }
        else          { dstb = Cv + (n0 - 512); dstride = 256; }
    } else { dstb = C + n0; dstride = (size_t)N; }

#pragma unroll
    for (int it = 0; it < 8; ++it) {
        const int tr = (tid >> 4) + it * 16;
        const int row = m0 + tr;
        if (row < M) {
            bf16x8 cv = *(const bf16x8*)((const char*)&sm.e.eps[0][0] + tr * 272 + tc * 2);
            float v[8];
#pragma unroll
            for (int j = 0; j < 8; ++j) v[j] = b2f((u16)cv[j]) + bb[j];
            if (RES == 1) {
                const float* rp = (const float*)res + (size_t)row * N + n0 + tc;
                float4 r0 = *(const float4*)(rp);
                float4 r1 = *(const float4*)(rp + 4);
                v[0] += r0.x; v[1] += r0.y; v[2] += r0.z; v[3] += r0.w;
                v[4] += r1.x; v[5] += r1.y; v[6] += r1.z; v[7] += r1.w;
            }
            if (RES == 2) {
                bf16x8 rv = *(const bf16x8*)((const u16*)res + (size_t)row * N + n0 + tc);
#pragma unroll
                for (int j = 0; j < 8; ++j) v[j] += b2f((u16)rv[j]);
            }
            if (RES == 3) {
                bf16x8 rv = *(const bf16x8*)((const u16*)res + (size_t)row * N + n0 + tc);
#pragma unroll
                for (int j = 0; j < 8; ++j) v[j] += b2f((u16)rv[j]) * ra8[j] + rb8[j];
            }
            if (RELU) {
#pragma unroll
                for (int j = 0; j < 8; ++j) v[j] = fmaxf(v[j], 0.f);
            }
            if (MODE == 2) {
#pragma unroll
                for (int j = 0; j < 8; ++j) { psum[j] += v[j]; psq[j] += v[j] * v[j]; }
            }
            u16 o[8];
#pragma unroll
            for (int j = 0; j < 8; ++j) o[j] = f2b(v[j]);
            *(bf16x8*)(dstb + (size_t)row * dstride + tc) = *(bf16x8*)o;
        }
    }

    if (MODE == 2) {
#pragma unroll
        for (int j = 0; j < 8; ++j) {
            atomicAdd(&sm.e.lsum[tc + j], psum[j]);
            atomicAdd(&sm.e.lsq[tc + j], psq[j]);
        }
        __syncthreads();
        if (tid < 128) {
            atomicAdd(&gsums[n0 + tid], sm.e.lsum[tid]);
            atomicAdd(&gsums[DM + n0 + tid], sm.e.lsq[tid]);
        }
    }
}

// ---------------------------------------------------------------------------
// Fused prep:
//   blocks [0,6250): x fp32 -> bf16 cast
//   blocks [6250,6378): weight transpose+cast via LDS 64x64 tiles (coalesced)
//   block 6378: bias pack
//   blocks [6379, ...): histogram of dst (CSR counts)
// ---------------------------------------------------------------------------
__global__ __launch_bounds__(256) void prep_kernel(
    const float* __restrict__ x, u16* __restrict__ xb,
    const float* __restrict__ Wq, const float* __restrict__ Wk,
    const float* __restrict__ Wv, const float* __restrict__ Wo,
    const float* __restrict__ W1, const float* __restrict__ W2,
    u16* __restrict__ wqkvt, u16* __restrict__ wot,
    u16* __restrict__ w1t, u16* __restrict__ w2t,
    const float* __restrict__ bq, const float* __restrict__ bk,
    const float* __restrict__ bv, float* __restrict__ bqkv,
    const int* __restrict__ edst, int* __restrict__ counts, int E)
{
    const int b = blockIdx.x;
    if (b < 6250) {
        const size_t i = ((size_t)b * 256 + threadIdx.x) * 8;
        float4 a = *(const float4*)(x + i);
        float4 c = *(const float4*)(x + i + 4);
        u16 o[8] = {f2b(a.x), f2b(a.y), f2b(a.z), f2b(a.w),
                    f2b(c.x), f2b(c.y), f2b(c.z), f2b(c.w)};
        *(bf16x8*)(xb + i) = *(bf16x8*)o;
    } else if (b < 6378) {
        __shared__ float tile[64][65];
        const int tb = b - 6250;
        const float* Wsrc; u16* outp; int srcN, outS, n0, k0;
        if (tb < 64) {
            const int mi = tb >> 4, ti = tb & 15;
            n0 = (ti & 3) * 64; k0 = (ti >> 2) * 64;
            srcN = 256; outS = 256;
            if (mi == 0)      { Wsrc = Wq; outp = wqkvt; }
            else if (mi == 1) { Wsrc = Wk; outp = wqkvt + 256 * 256; }
            else if (mi == 2) { Wsrc = Wv; outp = wqkvt + 512 * 256; }
            else              { Wsrc = Wo; outp = wot; }
        } else if (tb < 96) {
            const int ti = tb - 64;
            n0 = (ti & 7) * 64; k0 = (ti >> 3) * 64;
            srcN = 512; outS = 256; Wsrc = W1; outp = w1t;
        } else {
            const int ti = tb - 96;
            n0 = (ti & 3) * 64; k0 = (ti >> 2) * 64;
            srcN = 256; outS = 512; Wsrc = W2; outp = w2t;
        }
        const int kr = threadIdx.x >> 4, cc = (threadIdx.x & 15) * 4;
#pragma unroll
        for (int j = 0; j < 4; ++j) {
            float4 v = *(const float4*)(Wsrc + (size_t)(k0 + kr + j * 16) * srcN + n0 + cc);
            tile[kr + j * 16][cc + 0] = v.x;
            tile[kr + j * 16][cc + 1] = v.y;
            tile[kr + j * 16][cc + 2] = v.z;
            tile[kr + j * 16][cc + 3] = v.w;
        }
        __syncthreads();
        const int nr = threadIdx.x >> 3, c2 = (threadIdx.x & 7) * 8;
#pragma unroll
        for (int p = 0; p < 2; ++p) {
            const int row = nr + p * 32;
            u16 o[8];
#pragma unroll
            for (int j = 0; j < 8; ++j) o[j] = f2b(tile[c2 + j][row]);
            *(bf16x8*)(outp + (size_t)(n0 + row) * outS + k0 + c2) = *(bf16x8*)o;
        }
    } else if (b == 6378) {
        const int t = threadIdx.x;
        bqkv[t] = bq[t]; bqkv[t + 256] = bk[t]; bqkv[t + 512] = bv[t];
    } else {
        const int e = (b - 6379) * 256 + threadIdx.x;
        if (e < E) atomicAdd(&counts[edst[e]], 1);
    }
}

// ---------------------------------------------------------------------------
// BN1 fold: a,c from stats; w1t[n][k]*=a[k]; b1p = b1 + c @ W1; save a,c
// ---------------------------------------------------------------------------
__global__ __launch_bounds__(256) void bnfold_kernel(
    const float* __restrict__ sums, const float* __restrict__ g,
    const float* __restrict__ be, u16* __restrict__ w1t,
    const float* __restrict__ W1, const float* __restrict__ b1,
    float* __restrict__ b1p, float* __restrict__ affa, float* __restrict__ affc)
{
    const int blk = blockIdx.x;
    const int k = threadIdx.x;
    const float invM = 1.f / (float)NN;
    const float mean = sums[k] * invM;
    const float var = sums[DM + k] * invM - mean * mean;
    const float a = g[k] * rsqrtf(var + 1e-5f);
    const float c = be[k] - mean * a;
    if (blk < 64) {
#pragma unroll
        for (int j = 0; j < 8; ++j) {
            u16* pp = w1t + (size_t)(blk * 8 + j) * 256 + k;
            *pp = f2b(b2f(*pp) * a);
        }
    } else {
        __shared__ float cs[256];
        cs[k] = c;
        if (blk == 64) { affa[k] = a; affc[k] = c; }
        __syncthreads();
        const int n = (blk - 64) * 256 + k;
        float acc = b1[n];
        for (int kk = 0; kk < 256; ++kk)
            acc += cs[kk] * W1[(size_t)kk * 512 + n];
        b1p[n] = acc;
    }
}

// ---------------------------------------------------------------------------
// s[n,h] = dot(Q[n,h], K[n,h]) / sqrt(32)   (QK buffer [MP][512]: Q | K)
// ---------------------------------------------------------------------------
__global__ __launch_bounds__(256) void score_kernel(
    const u16* __restrict__ QK, float* __restrict__ s)
{
    const int t = blockIdx.x * 256 + threadIdx.x;
    if (t >= NN * NH) return;
    const int n = t >> 3, h = t & 7;
    const u16* qp = QK + (size_t)n * 512 + h * HD;
    const u16* kp = qp + DM;
    float acc = 0.f;
#pragma unroll
    for (int c = 0; c < HD; c += 8) {
        bf16x8 qa = *(const bf16x8*)(qp + c);
        bf16x8 ka = *(const bf16x8*)(kp + c);
#pragma unroll
        for (int j = 0; j < 8; ++j)
            acc += b2f((u16)qa[j]) * b2f((u16)ka[j]);
    }
    s[t] = acc * 0.17677669529663687f;
}

// ---------------------------------------------------------------------------
// single-block scan, 1024 threads, 4 elems/thread
// ---------------------------------------------------------------------------
__global__ __launch_bounds__(1024) void scan_kernel(
    const int* __restrict__ counts, int* __restrict__ offs,
    int* __restrict__ cursor, int n)
{
    __shared__ int wsum[16];
    __shared__ int srun;
    const int tid = threadIdx.x, lane = tid & 63, wid = tid >> 6;
    if (tid == 0) srun = 0;
    for (int base = 0; base < n; base += 4096) {
        const int idx = base + tid * 4;
        int v0 = 0, v1 = 0, v2 = 0, v3 = 0;
        if (idx + 3 < n) {
            int4 qv = *(const int4*)(counts + idx);
            v0 = qv.x; v1 = qv.y; v2 = qv.z; v3 = qv.w;
        } else if (idx < n) {
            v0 = counts[idx];
            if (idx + 1 < n) v1 = counts[idx + 1];
            if (idx + 2 < n) v2 = counts[idx + 2];
        }
        const int tsum = v0 + v1 + v2 + v3;
        int sc = tsum;
#pragma unroll
        for (int off = 1; off < 64; off <<= 1) {
            int t = __shfl_up(sc, off);
            if (lane >= off) sc += t;
        }
        if (lane == 63) wsum[wid] = sc;
        __syncthreads();
        if (tid < 16) {
            int w = wsum[tid];
#pragma unroll
            for (int off = 1; off < 16; off <<= 1) {
                int t = __shfl_up(w, off);
                if (tid >= off) w += t;
            }
            wsum[tid] = w;
        }
        __syncthreads();
        const int run = srun;
        int e = run + (wid ? wsum[wid - 1] : 0) + sc - tsum;
        if (idx < n)     { offs[idx] = e;     cursor[idx] = e; }
        e += v0;
        if (idx + 1 < n) { offs[idx + 1] = e; cursor[idx + 1] = e; }
        e += v1;
        if (idx + 2 < n) { offs[idx + 2] = e; cursor[idx + 2] = e; }
        e += v2;
        if (idx + 3 < n) { offs[idx + 3] = e; cursor[idx + 3] = e; }
        const int tot = wsum[15];
        __syncthreads();
        if (tid == 0) srun = run + tot;
    }
    if (tid == 0) offs[n] = srun;
}

__global__ __launch_bounds__(256) void fill_kernel(
    const int* __restrict__ src, const int* __restrict__ dst,
    int* __restrict__ cursor, int* __restrict__ csr_src, int E)
{
    const int e = blockIdx.x * 256 + threadIdx.x;
    if (e >= E) return;
    const int p = atomicAdd(&cursor[dst[e]], 1);
    csr_src[p] = src[e];
}

// ---------------------------------------------------------------------------
// Single-pass softmax-weighted V aggregation. One wave per node.
// Half-wave pairing: lanes 0-31 take even edges, 32-63 odd edges; each lane
// covers 8 features (16B loads); unroll x4 -> 8 edges in flight per wave.
// shfl_xor(32) merges halves at the end.
// ---------------------------------------------------------------------------
__global__ __launch_bounds__(256) void aggregate_kernel(
    const float* __restrict__ s, const u16* __restrict__ V,
    const int* __restrict__ offs, const int* __restrict__ srcs,
    u16* __restrict__ attn)
{
    const int n = (blockIdx.x * 256 + threadIdx.x) >> 6;
    const int lane = threadIdx.x & 63;
    if (n >= NN) return;
    const int base = offs[n];
    const int deg = offs[n + 1] - base;
    const int half = lane >> 5;
    const int l = lane & 31;
    const int f0 = l * 8;
    const int h0 = l >> 2;
    const float snh = s[(size_t)n * 8 + h0];

    float a[8] = {};
    float d = 0.f;
    if (half == 0) {  // self-loop
        const float w = __expf(fminf(leaky(2.f * snh), 30.f));
        d = w;
        bf16x8 vv = *(const bf16x8*)(V + (size_t)n * DM + f0);
#pragma unroll
        for (int j = 0; j < 8; ++j) a[j] = w * b2f((u16)vv[j]);
    }

    int i = 0;
    for (; i + 8 <= deg; i += 8) {
        int sr0, sr1, sr2, sr3;
        sr0 = srcs[base + i + 0 + half];
        sr1 = srcs[base + i + 2 + half];
        sr2 = srcs[base + i + 4 + half];
        sr3 = srcs[base + i + 6 + half];
        const float sv0 = s[(size_t)sr0 * 8 + h0];
        const float sv1 = s[(size_t)sr1 * 8 + h0];
        const float sv2 = s[(size_t)sr2 * 8 + h0];
        const float sv3 = s[(size_t)sr3 * 8 + h0];
        bf16x8 u0 = *(const bf16x8*)(V + (size_t)sr0 * DM + f0);
        bf16x8 u1 = *(const bf16x8*)(V + (size_t)sr1 * DM + f0);
        bf16x8 u2 = *(const bf16x8*)(V + (size_t)sr2 * DM + f0);
        bf16x8 u3 = *(const bf16x8*)(V + (size_t)sr3 * DM + f0);
        const float w0 = __expf(fminf(leaky(snh + sv0), 30.f));
        const float w1 = __expf(fminf(leaky(snh + sv1), 30.f));
        const float w2 = __expf(fminf(leaky(snh + sv2), 30.f));
        const float w3 = __expf(fminf(leaky(snh + sv3), 30.f));
        d += w0 + w1 + w2 + w3;
#pragma unroll
        for (int j = 0; j < 8; ++j)
            a[j] += w0 * b2f((u16)u0[j]) + w1 * b2f((u16)u1[j])
                  + w2 * b2f((u16)u2[j]) + w3 * b2f((u16)u3[j]);
    }
    for (; i + 2 <= deg; i += 2) {
        const int sr = srcs[base + i + half];
        const float sv = s[(size_t)sr * 8 + h0];
        bf16x8 uv = *(const bf16x8*)(V + (size_t)sr * DM + f0);
        const float w = __expf(fminf(leaky(snh + sv), 30.f));
        d += w;
#pragma unroll
        for (int j = 0; j < 8; ++j) a[j] += w * b2f((u16)uv[j]);
    }
    if (i < deg && half == 0) {
        const int sr = srcs[base + i];
        const float sv = s[(size_t)sr * 8 + h0];
        bf16x8 uv = *(const bf16x8*)(V + (size_t)sr * DM + f0);
        const float w = __expf(fminf(leaky(snh + sv), 30.f));
        d += w;
#pragma unroll
        for (int j = 0; j < 8; ++j) a[j] += w * b2f((u16)uv[j]);
    }

    d += __shfl_xor(d, 32);
#pragma unroll
    for (int j = 0; j < 8; ++j) a[j] += __shfl_xor(a[j], 32);

    if (half == 0) {
        const float rd = 1.f / d;
        u16 o[8];
#pragma unroll
        for (int j = 0; j < 8; ++j) o[j] = f2b(a[j] * rd);
        *(bf16x8*)(attn + (size_t)n * DM + f0) = *(bf16x8*)o;
    }
}

// ---------------------------------------------------------------------------
// BN2 apply -> fp32 out (stats pre-reduced by GEMM epilogue)
// ---------------------------------------------------------------------------
__global__ __launch_bounds__(256) void apply_out_kernel(
    const u16* __restrict__ z, const float* __restrict__ sums,
    const float* __restrict__ g, const float* __restrict__ b,
    float* __restrict__ out)
{
    const size_t i = ((size_t)blockIdx.x * 256 + threadIdx.x) * 8;
    if (i >= (size_t)NN * DM) return;
    const int f0 = (int)(i & (DM - 1));
    const float invM = 1.f / (float)NN;
    bf16x8 v = *(const bf16x8*)(z + i);
    float o[8];
#pragma unroll
    for (int j = 0; j < 8; ++j) {
        const int f = f0 + j;
        const float mean = sums[f] * invM;
        const float var = sums[DM + f] * invM - mean * mean;
        const float a = g[f] * rsqrtf(var + 1e-5f);
        o[j] = b2f((u16)v[j]) * a + (b[f] - mean * a);
    }
    *(float4*)(out + i)     = *(float4*)(o);
    *(float4*)(out + i + 4) = *(float4*)(o + 4);
}

// ---------------------------------------------------------------------------
extern "C" void kernel_launch(void* const* d_in, const int* in_sizes, int n_in,
                              void* d_out, int out_size, void* d_ws, size_t ws_size,
                              hipStream_t stream)
{
    const float* x   = (const float*)d_in[0];
    const int* eidx  = (const int*)d_in[1];
    const int E      = in_sizes[1] / 2;
    const int* esrc  = eidx;
    const int* edst  = eidx + E;
    const float* Wq = (const float*)d_in[2];  const float* bq = (const float*)d_in[3];
    const float* Wk = (const float*)d_in[4];  const float* bk = (const float*)d_in[5];
    const float* Wv = (const float*)d_in[6];  const float* bv = (const float*)d_in[7];
    const float* Wo = (const float*)d_in[8];  const float* bo = (const float*)d_in[9];
    const float* W1 = (const float*)d_in[10]; const float* b1 = (const float*)d_in[11];
    const float* W2 = (const float*)d_in[12]; const float* b2 = (const float*)d_in[13];
    const float* g1 = (const float*)d_in[14]; const float* be1 = (const float*)d_in[15];
    const float* g2 = (const float*)d_in[16]; const float* be2 = (const float*)d_in[17];
    float* out = (float*)d_out;

    // ---- workspace layout (bf16 = u16) ----
    u16* xb  = (u16*)d_ws;                        // [MP*256]  x(bf16) -> y
    u16* qk  = xb + (size_t)MP * DM;              // [MP*512]  Q|K -> ff1
    u16* vb  = qk + (size_t)MP * 512;             // [MP*256]  compact V
    u16* attn = vb + (size_t)MP * DM;             // [MP*256]  attn -> z
    float* sS = (float*)(attn + (size_t)MP * DM); // [NN*8]
    int* counts = (int*)(sS + (size_t)NN * NH);
    int* offs   = counts + NN;                    // NN+1
    int* cursor = offs + NN + 1;
    int* csr    = cursor + NN;                    // E
    uintptr_t p = (uintptr_t)(csr + E);
    p = (p + 15) & ~(uintptr_t)15;
    u16* wqkvt = (u16*)p;                         // [768*256]
    u16* wot   = wqkvt + 768 * 256;               // [256*256]
    u16* w1t   = wot + 256 * 256;                 // [512*256]
    u16* w2t   = w1t + 512 * 256;                 // [256*512]
    float* bqkv   = (float*)(w2t + 256 * 512);    // [768]
    float* bnsum1 = bqkv + 768;                   // [512]
    float* bnsum2 = bnsum1 + 512;                 // [512]
    float* b1p    = bnsum2 + 512;                 // [512]
    float* affa   = b1p + 512;                    // [256]
    float* affc   = affa + 256;                   // [256]

    const dim3 blk(256);
    const int elem_grid = (NN * DM / 8 + 255) / 256;
    const int hist_blks = (E + 255) / 256;

    // ---- zero counters; fused prep (cast + weight packing + bias + hist) ----
    hipMemsetAsync(counts, 0, sizeof(int) * NN, stream);
    hipMemsetAsync(bnsum1, 0, sizeof(float) * 1024, stream);
    prep_kernel<<<6379 + hist_blks, blk, 0, stream>>>(
        x, xb, Wq, Wk, Wv, Wo, W1, W2, wqkvt, wot, w1t, w2t,
        bq, bk, bv, bqkv, edst, counts, E);
    scan_kernel<<<1, 1024, 0, stream>>>(counts, offs, cursor, NN);
    fill_kernel<<<hist_blks, blk, 0, stream>>>(esrc, edst, cursor, csr, E);

    // ---- fused QKV projection (Q,K -> qk; V -> compact vb) ----
    gemm_bf16<0, 0, 256, 1><<<dim3(6, MP / 128), blk, 0, stream>>>(
        xb, wqkvt, bqkv, nullptr, nullptr, nullptr, qk, vb, nullptr, NN, 768);

    // ---- per-node scores ----
    score_kernel<<<(NN * NH + 255) / 256, blk, 0, stream>>>(qk, sS);

    // ---- single-pass softmax + V aggregation ----
    aggregate_kernel<<<(NN + 3) / 4, blk, 0, stream>>>(sS, vb, offs, csr, attn);

    // ---- O-projection + residual + fused BN1 stats: y = x + attn@Wo + bo ----
    gemm_bf16<0, 1, 256, 2><<<dim3(2, MP / 128), blk, 0, stream>>>(
        attn, wot, bo, x, nullptr, nullptr, xb, nullptr, bnsum1, NN, DM);

    // ---- fold BN1 into W1/b1 (w1t *= a, b1p = b1 + c@W1; save a,c) ----
    bnfold_kernel<<<66, blk, 0, stream>>>(bnsum1, g1, be1, w1t, W1, b1,
                                          b1p, affa, affc);

    // ---- FF1: ff1 = relu(y @ (aW1) + b1')  (into qk region) ----
    gemm_bf16<1, 0, 256, 0><<<dim3(4, MP / 128), blk, 0, stream>>>(
        xb, w1t, b1p, nullptr, nullptr, nullptr, qk, nullptr, nullptr, NN, DFF);

    // ---- FF2 + affine residual + fused BN2 stats: z = (a*y+c) + ff1@W2 + b2 ----
    gemm_bf16<0, 3, 512, 2><<<dim3(2, MP / 128), blk, 0, stream>>>(
        qk, w2t, b2, xb, affa, affc, attn, nullptr, bnsum2, NN, DM);

    // ---- BN2 apply -> out (fp32) ----
    apply_out_kernel<<<elem_grid, blk, 0, stream>>>(attn, bnsum2, g2, be2, out);
}